// Round 11
// baseline (1703.391 us; speedup 1.0000x reference)
//
#include <hip/hip_runtime.h>
#include <hip/hip_bf16.h>
#include <math.h>

#define H_ 200
#define W_ 272
#define C_ 256
#define HW 54400
#define NANCH 489600
#define PRE_N 6000
#define POST_N 1000
#define NWORDS 94    // ceil(6000/64)
#define CHUNK_W 2720 // 8 ic * 10 rows * 34 cols halo
#define SELCAP 16384
#define NSEG 16      // histogram privatization copies

// ---- workspace layout (bytes) ----
#define X_OFF       0ull                 // 256*54400*4 = 55,705,600
#define CONF_OFF    55705600ull          // 489600*4   =  1,958,400
#define TILEC_OFF   57664000ull          // 225*4 tile counters (old hist1 slot)
#define SEL_OFF     57926144ull          // 16384*8    =    131,072
#define SCAL_OFF    58188288ull          // 64*4
#define TOPIDX_OFF  58254080ull          // 6000*4
#define BOXES_OFF   58278080ull          // 6000*4*4
#define VALID_OFF   58374080ull          // 6000*4
#define MASK_OFF    58398080ull          // 6000*94*8 = 4,512,000 (w1r + histc live here pre-k_mask)
#define HISTC_OFF   60757376ull          // MASK_OFF + 2,359,296 (w1r); 16*65536*4 = 4,194,304
#define WCR_OFF     65269376ull          // 9*256*4
#define XT_OFF      65278592ull          // optional: 54400*256*4 = 55,705,600 (transposed x)
#define WS_NEED_XT  (XT_OFF + 55705600ull)

__device__ __forceinline__ unsigned fkey(float fv) {
    unsigned u = __float_as_uint(fv);
    return (u & 0x80000000u) ? ~u : (u | 0x80000000u);  // monotone: bigger float -> bigger key
}

// ---- weight repack + init. w1 OIHW -> w1r[((wg8*256+ic)*9+t)*8+o];
// histc[16][65536]=0 (uint2 stores, 2 words/thread); tilec[225]=0;
// wcr repack moved here (stream-ordered before conv -> safe for fused cls). ----
__global__ __launch_bounds__(256) void k_repack(const float* __restrict__ w1,
                                                float* __restrict__ w1r,
                                                unsigned* __restrict__ histc,
                                                unsigned* __restrict__ tilec,
                                                const float* __restrict__ wcls,
                                                float* __restrict__ wcr) {
    int d = blockIdx.x * 256 + threadIdx.x;   // 589,824 total
    if (d < (NSEG * 65536) / 2) { uint2 z; z.x = 0u; z.y = 0u; ((uint2*)histc)[d] = z; }
    if (d < 225) tilec[d] = 0u;
    if (d < 2304) {
        int a = d / 256, c = d % 256;
        wcr[c * 9 + a] = wcls[d];
    }
    int o = d & 7;
    int q = d >> 3;            // icg*9 + t
    int t = q % 9;
    int icg = q / 9;           // wg8*256 + ic
    int wg8 = icg >> 8, ic = icg & 255;
    w1r[d] = w1[((size_t)(wg8 * 8 + o) * 256 + ic) * 9 + t];
}

// ---- 3x3 conv + bias + relu, with FUSED 1x1 cls conv + histogram.
// Conv main loop is the R2-proven structure (818us): 32x8 tile, 8 oc x 4 px
// per lane, 8-ic double buffer, one barrier/chunk, repacked uniform weights.
// DO NOT change the main loop (R1/R3/R4/R6 all regressed).
// Fusion: each tile has 8 z-blocks; after epilogue stores + device fence,
// the LAST z-block (per-tile atomic counter) runs the cls phase for the
// tile's 256 pixels inline — same ILP-8 c-ascending FMA order as the old
// k_cls -> bitwise-identical conf. Runs during conv's drain on idle CUs. ----
__global__ __launch_bounds__(256) void k_conv1(const float* __restrict__ f,
                                               const float* __restrict__ w1r,
                                               const float* __restrict__ b1,
                                               float* __restrict__ xo,
                                               float* __restrict__ xt,
                                               unsigned* __restrict__ scal,
                                               unsigned long long* __restrict__ sel,
                                               const float* __restrict__ wcr,
                                               const float* __restrict__ bc,
                                               float* __restrict__ conf,
                                               unsigned* __restrict__ histc,
                                               unsigned* __restrict__ tilec) {
    __shared__ __align__(16) float sI[2][2880];   // 2 x 11,520 B
    __shared__ unsigned isLast;
    int tid = threadIdx.x;
    int fb = blockIdx.x + 9 * (blockIdx.y + 25 * blockIdx.z);
    int tileId = blockIdx.x + 9 * blockIdx.y;     // 225 tiles
    // workspace init: 64 scal words + 32768 sel-words
    {
        int g = fb * 256 + tid;
        if (g < 64) scal[g] = 0u;
        else if (g < 32832) ((unsigned*)sel)[g - 64] = 0xFFFFFFFFu;
    }
    int lane = tid & 63;
    int wgl = __builtin_amdgcn_readfirstlane(tid >> 6);
    int xg = lane & 7;
    int yg = lane >> 3;
    int X0 = blockIdx.x * 32;
    int Y0 = blockIdx.y * 8;
    int wg = blockIdx.z * 4 + wgl;   // oc-group of 8, wave-uniform
    int y = Y0 + yg;
    int xbase = X0 + xg * 4;

    int off[11]; int lds[11]; bool ok[11];
#pragma unroll
    for (int it = 0; it < 11; it++) {
        int l = tid + it * 256;
        int ci = l / 340; int r = l - ci * 340; int ry = r / 34; int rx = r - ry * 34;
        int gx = X0 - 1 + rx, gy = Y0 - 1 + ry;
        ok[it] = (l < CHUNK_W) && gx >= 0 && gx < W_ && gy >= 0 && gy < H_;
        off[it] = ci * HW + gy * W_ + gx;
        lds[it] = (ci * 10 + ry) * 36 + rx;
    }
    float rbuf[11];
#pragma unroll
    for (int it = 0; it < 11; it++)
        rbuf[it] = ok[it] ? f[off[it]] : 0.f;
#pragma unroll
    for (int it = 0; it < 11; it++)
        if (tid + it * 256 < CHUNK_W) sI[0][lds[it]] = rbuf[it];
    __syncthreads();

    float acc[8][4];
#pragma unroll
    for (int o = 0; o < 8; o++)
#pragma unroll
        for (int i = 0; i < 4; i++) acc[o][i] = 0.f;

    const float* wbase = w1r + (size_t)wg * (256 * 72);  // repacked, wave-uniform

    int cur = 0;
    for (int ic0 = 0; ic0 < 256; ic0 += 8) {
        if (ic0 < 248) {
            const float* fn = f + (size_t)(ic0 + 8) * HW;
#pragma unroll
            for (int it = 0; it < 11; it++)
                rbuf[it] = ok[it] ? fn[off[it]] : 0.f;
        }
        const float* sbuf = sI[cur];
        for (int ci = 0; ci < 8; ci++) {
            const float* wci = wbase + (ic0 + ci) * 72;   // 9 taps x 8 oc, contiguous
#pragma unroll
            for (int ky = 0; ky < 3; ky++) {
                const float* irow = &sbuf[(ci * 10 + yg + ky) * 36 + xg * 4];
                float4 va = *(const float4*)irow;
                float2 vb = *(const float2*)(irow + 4);
                float in[6] = {va.x, va.y, va.z, va.w, vb.x, vb.y};
#pragma unroll
                for (int kx = 0; kx < 3; kx++) {
                    const float* w8 = wci + (ky * 3 + kx) * 8;
#pragma unroll
                    for (int o = 0; o < 8; o++) {
                        float w = w8[o];   // s_load from contiguous 32B group
#pragma unroll
                        for (int i = 0; i < 4; i++)
                            acc[o][i] = fmaf(w, in[i + kx], acc[o][i]);
                    }
                }
            }
        }
        if (ic0 < 248) {
#pragma unroll
            for (int it = 0; it < 11; it++)
                if (tid + it * 256 < CHUNK_W) sI[cur ^ 1][lds[it]] = rbuf[it];
        }
        __syncthreads();
        cur ^= 1;
    }
    // epilogue: same per-element ops/order (bias add, relu)
    float vout[8][4];
#pragma unroll
    for (int o = 0; o < 8; o++) {
        float bv = b1[wg * 8 + o];
#pragma unroll
        for (int i = 0; i < 4; i++)
            vout[o][i] = fmaxf(acc[o][i] + bv, 0.f);
    }
#pragma unroll
    for (int o = 0; o < 8; o++) {
        int oc = wg * 8 + o;
        float* orow = xo + (size_t)oc * HW + y * W_ + xbase;
        if (xbase + 3 < W_) {
            *(float4*)orow = make_float4(vout[o][0], vout[o][1], vout[o][2], vout[o][3]);
        } else {
            for (int i = 0; i < 4; i++)
                if (xbase + i < W_) orow[i] = vout[o][i];
        }
    }
    if (xt) {   // transposed copy (identical values, different address)
#pragma unroll
        for (int i = 0; i < 4; i++) {
            if (xbase + i < W_) {
                size_t px = (size_t)(y * W_ + xbase + i);
                *(float4*)&xt[px * 256 + wg * 8] =
                    make_float4(vout[0][i], vout[1][i], vout[2][i], vout[3][i]);
                *(float4*)&xt[px * 256 + wg * 8 + 4] =
                    make_float4(vout[4][i], vout[5][i], vout[6][i], vout[7][i]);
            }
        }
    }

    // ---- fused cls phase: last z-block of this tile runs it ----
    __threadfence();          // release: this thread's xo/xt stores device-visible
    __syncthreads();          // all threads of block have fenced
    if (tid == 0) {
        unsigned prev = atomicAdd(&tilec[tileId], 1u);
        isLast = (prev == 7u) ? 1u : 0u;
    }
    __syncthreads();
    if (!isLast) return;
    __threadfence();          // acquire: see the other 7 blocks' xo stores

    int pxc = X0 + (tid & 31);
    int pyc = Y0 + (tid >> 5);
    if (pxc >= W_) return;
    int p = pyc * W_ + pxc;
    unsigned* myh = histc + (fb & (NSEG - 1)) * 65536;
    float acc9[9];
#pragma unroll
    for (int a = 0; a < 9; a++) acc9[a] = 0.f;
    for (int c0 = 0; c0 < 256; c0 += 8) {
        float xv8[8];
#pragma unroll
        for (int j = 0; j < 8; j++)
            xv8[j] = xo[(c0 + j) * HW + p];    // 8 independent loads in flight
#pragma unroll
        for (int j = 0; j < 8; j++) {
            const float* wp = wcr + (c0 + j) * 9;  // uniform -> s_load
#pragma unroll
            for (int a = 0; a < 9; a++) acc9[a] = fmaf(wp[a], xv8[j], acc9[a]);
        }
    }
#pragma unroll
    for (int a = 0; a < 9; a++) {
        float v = acc9[a] + bc[a];
        conf[p * 9 + a] = v;
        atomicAdd(&myh[fkey(v) >> 16], 1u);
    }
}

// ---- descending scan over the segment-summed 65536-bin histogram. ----
__global__ __launch_bounds__(1024) void k_scan(const unsigned* __restrict__ histc,
                                               unsigned* scal) {
    __shared__ unsigned ssum[1024];
    int t = threadIdx.x;
    int base = 65535 - t * 64;
    unsigned s = 0;
    for (int seg = 0; seg < NSEG; seg++) {
        const uint4* hp = (const uint4*)(histc + seg * 65536 + (base - 63));
#pragma unroll
        for (int k = 0; k < 16; k++) { uint4 v = hp[k]; s += v.x + v.y + v.z + v.w; }
    }
    ssum[t] = s;
    __syncthreads();
    for (int off = 1; off < 1024; off <<= 1) {
        unsigned v = (t >= off) ? ssum[t - off] : 0u;
        __syncthreads();
        ssum[t] += v;
        __syncthreads();
    }
    unsigned incl = ssum[t], excl = incl - s;
    if (excl < 6000u && 6000u <= incl) {
        unsigned run = excl;
        bool found = false;
        for (int pass = 0; pass < 2 && !found; pass++) {
            unsigned c32[32];
#pragma unroll
            for (int j = 0; j < 32; j++) {
                int idx = base - (pass * 32 + j);
                unsigned cj = 0;
#pragma unroll
                for (int seg = 0; seg < NSEG; seg++) cj += histc[seg * 65536 + idx];
                c32[j] = cj;
            }
            for (int j = 0; j < 32; j++) {
                if (run + c32[j] >= 6000u) {
                    scal[0] = (unsigned)(base - (pass * 32 + j));
                    scal[1] = run;
                    found = true;
                    break;
                }
                run += c32[j];
            }
        }
    }
}

// ---- single-pass gather: block-aggregated atomics (R10, proven -66us). ----
__global__ __launch_bounds__(256) void k_gather(const float* __restrict__ conf,
                                                unsigned* scal, unsigned long long* sel) {
    __shared__ unsigned lcA, lcB, bA, bB;
    int n = blockIdx.x * 256 + threadIdx.x;
    bool inr = n < NANCH;
    if (threadIdx.x == 0) { lcA = 0u; lcB = 0u; }
    __syncthreads();
    unsigned B1 = scal[0], cnt1 = scal[1];
    unsigned key = 0, off = 0;
    int cls = 0;
    if (inr) {
        key = fkey(conf[n]);
        unsigned pre = key >> 16;
        if (pre > B1)       { cls = 1; off = atomicAdd(&lcA, 1u); }
        else if (pre == B1) { cls = 2; off = atomicAdd(&lcB, 1u); }
    }
    __syncthreads();
    if (threadIdx.x == 0) {
        bA = lcA ? atomicAdd(&scal[4], lcA) : 0u;
        bB = lcB ? atomicAdd(&scal[36], lcB) : 0u;
    }
    __syncthreads();
    if (cls) {
        unsigned long long kk = ((unsigned long long)(~key) << 32) | (unsigned)n;  // smaller = better
        if (cls == 1) {
            sel[bA + off] = kk;                  // [0, cnt1) by construction
        } else {
            unsigned pos = cnt1 + bB + off;
            if (pos < SELCAP) sel[pos] = kk;
        }
    }
}

// ---- exact rank by pairwise comparison over [0, SELCAP) with early-out ----
__global__ __launch_bounds__(256) void k_rank(const unsigned* __restrict__ scal,
                                              const unsigned long long* __restrict__ sel,
                                              unsigned* __restrict__ topidx) {
    __shared__ unsigned long long tile[2048];
    unsigned filled = scal[1] + scal[36];
    if (filled > SELCAP) filled = SELCAP;
    int i = blockIdx.x * 256 + threadIdx.x;
    unsigned long long mykey = sel[i];
    int rank = 0;
    for (int t0 = 0; t0 < SELCAP; t0 += 2048) {
        if (t0 >= (int)filled) break;   // uniform across block
        __syncthreads();
        for (int l = threadIdx.x; l < 2048; l += 256)
            tile[l] = sel[t0 + l];
        __syncthreads();
        for (int l = 0; l < 2048; l += 4) {
            ulonglong2 p = *(const ulonglong2*)&tile[l];
            ulonglong2 q = *(const ulonglong2*)&tile[l + 2];
            rank += (p.x < mykey) + (p.y < mykey) + (q.x < mykey) + (q.y < mykey);
        }
    }
    if (i < (int)filled && rank < PRE_N)
        topidx[rank] = (unsigned)(mykey & 0xFFFFFFFFull);
}

// ---- per-proposal: reg conv (4 channels), anchor, decode, clip, valid. ----
__global__ __launch_bounds__(256) void k_prop(const float* __restrict__ x,
                                              const float* __restrict__ xt,
                                              const float* __restrict__ wreg,
                                              const float* __restrict__ breg,
                                              const unsigned* __restrict__ topidx,
                                              const int* __restrict__ imh, const int* __restrict__ imw,
                                              float* __restrict__ boxes, int* __restrict__ valid) {
    int r = blockIdx.x * 4 + (threadIdx.x >> 6);   // 1500 blocks x 4 waves = 6000
    int lane = threadIdx.x & 63;
    unsigned n = topidx[r];
    int a = (int)(n % 9u); int p = (int)(n / 9u);
    const float* wr = wreg + (4 * a) * 256;
    float xv4[4], w0[4], w1[4], w2[4], w3[4];
    if (xt) {
        const float* xp = xt + (size_t)p * 256;
#pragma unroll
        for (int j = 0; j < 4; j++) {
            int c = lane + 64 * j;
            xv4[j] = xp[c];
            w0[j] = wr[c]; w1[j] = wr[256 + c]; w2[j] = wr[512 + c]; w3[j] = wr[768 + c];
        }
    } else {
#pragma unroll
        for (int j = 0; j < 4; j++) {
            int c = lane + 64 * j;
            xv4[j] = x[c * HW + p];
            w0[j] = wr[c]; w1[j] = wr[256 + c]; w2[j] = wr[512 + c]; w3[j] = wr[768 + c];
        }
    }
    float s0 = 0, s1 = 0, s2 = 0, s3 = 0;
#pragma unroll
    for (int j = 0; j < 4; j++) {
        s0 = fmaf(w0[j], xv4[j], s0);
        s1 = fmaf(w1[j], xv4[j], s1);
        s2 = fmaf(w2[j], xv4[j], s2);
        s3 = fmaf(w3[j], xv4[j], s3);
    }
#pragma unroll
    for (int off = 32; off >= 1; off >>= 1) {
        s0 += __shfl_down(s0, off);
        s1 += __shfl_down(s1, off);
        s2 += __shfl_down(s2, off);
        s3 += __shfl_down(s3, off);
    }
    if (lane == 0) {
        float dx = s0 + breg[4 * a], dy = s1 + breg[4 * a + 1];
        float dw = s2 + breg[4 * a + 2], dh = s3 + breg[4 * a + 3];
        int wi = p % W_, hi = p / W_;
        const double SC[3] = {32.0, 64.0, 128.0};
        const double RT[3] = {0.5, 1.0, 2.0};
        double sd = SC[a / 3], rd = RT[a % 3];
        double wb = sd * sqrt(1.0 / rd), hb = sd * sqrt(rd);
        float bx1 = (float)(-wb * 0.5), by1 = (float)(-hb * 0.5);
        float bx2 = (float)(wb * 0.5),  by2 = (float)(hb * 0.5);
        float cxs = ((float)wi + 0.5f) * 4.0f, cys = ((float)hi + 0.5f) * 4.0f;
        float x1a = cxs + bx1, y1a = cys + by1, x2a = cxs + bx2, y2a = cys + by2;
        float wa = x2a - x1a, ha = y2a - y1a;
        float cxa = x1a + 0.5f * wa, cya = y1a + 0.5f * ha;
        float cx = dx * wa + cxa, cy = dy * ha + cya;
        float ww = expf(dw) * wa, hh = expf(dh) * ha;
        float X1 = cx - 0.5f * ww, Y1 = cy - 0.5f * hh;
        float X2 = cx + 0.5f * ww, Y2 = cy + 0.5f * hh;
        float Wf = (float)(*imw), Hf = (float)(*imh);
        X1 = fminf(fmaxf(X1, 0.f), Wf); Y1 = fminf(fmaxf(Y1, 0.f), Hf);
        X2 = fminf(fmaxf(X2, 0.f), Wf); Y2 = fminf(fmaxf(Y2, 0.f), Hf);
        boxes[4 * r] = X1; boxes[4 * r + 1] = Y1; boxes[4 * r + 2] = X2; boxes[4 * r + 3] = Y2;
        valid[r] = ((X2 - X1) >= 1.0f && (Y2 - Y1) >= 1.0f) ? 1 : 0;
    }
}

// ---- NMS IoU bitmask. Lower-triangle blocks skipped (never read). ----
__global__ __launch_bounds__(256) void k_mask(const float* __restrict__ boxes,
                                              unsigned long long* __restrict__ mask) {
    __shared__ float jb[256];
    int jw = blockIdx.x;
    if (jw * 64 + 63 < (int)blockIdx.y * 256) return;   // never-read region
    int i = blockIdx.y * 256 + threadIdx.x;
    {
        int idx = jw * 256 + threadIdx.x;
        jb[threadIdx.x] = (idx < PRE_N * 4) ? boxes[idx] : 0.f;
    }
    __syncthreads();
    if (i >= PRE_N) return;
    float4 ab = *(const float4*)&boxes[4 * i];
    float ax1 = ab.x, ay1 = ab.y, ax2 = ab.z, ay2 = ab.w;
    float aarea = (ax2 - ax1) * (ay2 - ay1);
    unsigned long long m = 0;
    int jbase = jw * 64;
    for (int b = 0; b < 64; b++) {
        int j = jbase + b;
        if (j <= i || j >= PRE_N) continue;
        float bx1 = jb[4 * b], by1 = jb[4 * b + 1], bx2 = jb[4 * b + 2], by2 = jb[4 * b + 3];
        float barea = (bx2 - bx1) * (by2 - by1);
        float xx1 = fmaxf(ax1, bx1), yy1 = fmaxf(ay1, by1);
        float xx2 = fminf(ax2, bx2), yy2 = fminf(ay2, by2);
        float w = fmaxf(xx2 - xx1, 0.f), h = fmaxf(yy2 - yy1, 0.f);
        float inter = w * h;
        float iou = inter / (aarea + barea - inter + 1e-9f);
        if (iou > 0.7f) m |= (1ull << b);
    }
    mask[(size_t)i * NWORDS + jw] = m;
}

// ---- greedy scan: serial walk on wave 0 via register diag rows + shfl ----
__global__ __launch_bounds__(256) void k_scan_nms(const unsigned long long* __restrict__ mask,
                                                  const int* __restrict__ valid,
                                                  const float* __restrict__ boxes,
                                                  float* __restrict__ out) {
    __shared__ unsigned long long diag[NWORDS][64];   // 48,128 B
    __shared__ unsigned long long removed[NWORDS];
    __shared__ unsigned long long validw[NWORDS];
    __shared__ int keepList[POST_N];
    __shared__ int cnt;
    __shared__ unsigned long long keptbits;
    int t = threadIdx.x;
    if (t < NWORDS) { removed[t] = 0ull; validw[t] = 0ull; }
    if (t == 0) cnt = 0;
    __syncthreads();
    for (int l = t; l < NWORDS * 64; l += 256) {
        int w = l >> 6, b = l & 63;
        int i = w * 64 + b;
        diag[w][b] = (i < PRE_N) ? mask[(size_t)i * NWORDS + w] : 0ull;
    }
    for (int i = t; i < PRE_N; i += 256)
        if (valid[i]) atomicOr(&validw[i >> 6], 1ull << (i & 63));
    __syncthreads();
    for (int w = 0; w < NWORDS; w++) {
        unsigned long long candw = validw[w] & ~removed[w];
        if (!candw) continue;
        if (t < 64) {
            unsigned long long mydiag = diag[w][t];   // lane t owns row (w*64+t)'s word w
            unsigned long long cand = candw;
            unsigned long long kb = 0ull;
            int c = cnt;
            while (cand && c < POST_N) {
                int b = __ffsll((unsigned long long)cand) - 1;
                unsigned long long sup = __shfl(mydiag, b);   // register, ~5 cyc
                if (t == 0) keepList[c] = w * 64 + b;
                c++;
                kb |= 1ull << b;
                cand &= ~(1ull << b);
                cand &= ~sup;
            }
            if (t == 0) { cnt = c; keptbits = kb; }
        }
        __syncthreads();
        if (cnt >= POST_N) break;
        unsigned long long kb = keptbits;
        if (kb) {
            for (int w2 = w + 1 + t; w2 < NWORDS; w2 += 256) {
                unsigned long long acc2 = removed[w2];
                unsigned long long tt = kb;
                while (tt) {
                    int b = __ffsll((unsigned long long)tt) - 1;
                    tt &= tt - 1;
                    acc2 |= mask[(size_t)(w * 64 + b) * NWORDS + w2];
                }
                removed[w2] = acc2;
            }
        }
        __syncthreads();
    }
    __syncthreads();
    int c = cnt;
    for (int e = t; e < POST_N * 4; e += 256) {
        int r = e >> 2;
        out[e] = (r < c) ? boxes[4 * keepList[r] + (e & 3)] : 0.f;
    }
}

extern "C" void kernel_launch(void* const* d_in, const int* in_sizes, int n_in,
                              void* d_out, int out_size, void* d_ws, size_t ws_size,
                              hipStream_t stream) {
    const float* feature = (const float*)d_in[0];
    const float* w1   = (const float*)d_in[1];
    const float* b1   = (const float*)d_in[2];
    const float* wcls = (const float*)d_in[3];
    const float* bcls = (const float*)d_in[4];
    const float* wreg = (const float*)d_in[5];
    const float* breg = (const float*)d_in[6];
    const int* imh = (const int*)d_in[7];
    const int* imw = (const int*)d_in[8];

    char* ws = (char*)d_ws;
    float* xbuf  = (float*)(ws + X_OFF);
    float* conf  = (float*)(ws + CONF_OFF);
    unsigned* tilec = (unsigned*)(ws + TILEC_OFF);
    unsigned* scal  = (unsigned*)(ws + SCAL_OFF);
    unsigned long long* sel = (unsigned long long*)(ws + SEL_OFF);
    unsigned* topidx = (unsigned*)(ws + TOPIDX_OFF);
    float* boxes = (float*)(ws + BOXES_OFF);
    int* valid   = (int*)(ws + VALID_OFF);
    unsigned long long* mask = (unsigned long long*)(ws + MASK_OFF);
    float* w1r = (float*)(ws + MASK_OFF);          // dead after k_conv1; overwritten by k_mask
    unsigned* histc = (unsigned*)(ws + HISTC_OFF); // 16 segments; dead after k_scan
    float* wcr = (float*)(ws + WCR_OFF);
    float* xt  = (ws_size >= WS_NEED_XT) ? (float*)(ws + XT_OFF) : (float*)0;
    float* outF = (float*)d_out;

    hipLaunchKernelGGL(k_repack, dim3(2304), dim3(256), 0, stream, w1, w1r, histc, tilec, wcls, wcr);
    hipLaunchKernelGGL(k_conv1,  dim3(9, 25, 8), dim3(256), 0, stream,
                       feature, w1r, b1, xbuf, xt, scal, sel, wcr, bcls, conf, histc, tilec);
    hipLaunchKernelGGL(k_scan,   dim3(1),    dim3(1024), 0, stream, histc, scal);
    hipLaunchKernelGGL(k_gather, dim3(1913), dim3(256), 0, stream, conf, scal, sel);
    hipLaunchKernelGGL(k_rank,   dim3(64),   dim3(256), 0, stream, scal, sel, topidx);
    hipLaunchKernelGGL(k_prop,   dim3(1500), dim3(256), 0, stream, xbuf, xt, wreg, breg, topidx, imh, imw, boxes, valid);
    hipLaunchKernelGGL(k_mask,   dim3(NWORDS, 24), dim3(256), 0, stream, boxes, mask);
    hipLaunchKernelGGL(k_scan_nms, dim3(1), dim3(256), 0, stream, mask, valid, boxes, outF);
}

// Round 12
// 1524.671 us; speedup vs baseline: 1.1172x; 1.1172x over previous
//
#include <hip/hip_runtime.h>
#include <hip/hip_bf16.h>
#include <math.h>

#define H_ 200
#define W_ 272
#define C_ 256
#define HW 54400
#define NANCH 489600
#define PRE_N 6000
#define POST_N 1000
#define NWORDS 94    // ceil(6000/64)
#define CHUNK_W 2720 // 8 ic * 10 rows * 34 cols halo
#define SELCAP 16384
#define NSEG 16      // histogram privatization copies

// ---- workspace layout (bytes) ----
#define X_OFF       0ull                 // 256*54400*4 = 55,705,600
#define CONF_OFF    55705600ull          // 489600*4   =  1,958,400
#define SEL_OFF     57926144ull          // 16384*8    =    131,072
#define SCAL_OFF    58188288ull          // 64*4
#define TOPIDX_OFF  58254080ull          // 6000*4
#define BOXES_OFF   58278080ull          // 6000*4*4
#define VALID_OFF   58374080ull          // 6000*4
#define MASK_OFF    58398080ull          // 6000*94*8 = 4,512,000 (w1r + histc live here pre-k_mask)
#define HISTC_OFF   60757376ull          // MASK_OFF + 2,359,296 (w1r); 16*65536*4 = 4,194,304
#define WCR_OFF     65269376ull          // 9*256*4
#define XT_OFF      65278592ull          // optional: 54400*256*4 = 55,705,600 (transposed x)
#define WS_NEED_XT  (XT_OFF + 55705600ull)

__device__ __forceinline__ unsigned fkey(float fv) {
    unsigned u = __float_as_uint(fv);
    return (u & 0x80000000u) ? ~u : (u | 0x80000000u);  // monotone: bigger float -> bigger key
}

// ---- weight repack + init. w1 OIHW -> w1r[((wg8*256+ic)*9+t)*8+o];
// histc[16][65536]=0 (uint2); wcr repack (stream-ordered before k_cls). ----
__global__ __launch_bounds__(256) void k_repack(const float* __restrict__ w1,
                                                float* __restrict__ w1r,
                                                unsigned* __restrict__ histc,
                                                const float* __restrict__ wcls,
                                                float* __restrict__ wcr) {
    int d = blockIdx.x * 256 + threadIdx.x;   // 589,824 total
    if (d < (NSEG * 65536) / 2) { uint2 z; z.x = 0u; z.y = 0u; ((uint2*)histc)[d] = z; }
    if (d < 2304) {
        int a = d / 256, c = d % 256;
        wcr[c * 9 + a] = wcls[d];
    }
    int o = d & 7;
    int q = d >> 3;            // icg*9 + t
    int t = q % 9;
    int icg = q / 9;           // wg8*256 + ic
    int wg8 = icg >> 8, ic = icg & 255;
    w1r[d] = w1[((size_t)(wg8 * 8 + o) * 256 + ic) * 9 + t];
}

// ---- 3x3 conv + bias + relu. R2-proven structure (818us): 32x8 tile,
// 8 oc x 4 px/lane, 8-ic double buffer, 1800 blocks, one barrier/chunk,
// b128/b64 LDS reads, repacked contiguous uniform weights. DO NOT change
// the main loop (R1/R3/R4/R6 regressed). NO fusion/fences (R11 regressed
// +265us: device fences + scattered cls reads; launch boundaries are ~free).
// Epilogue also writes transposed xt[p*256+oc] (R8, ~free). ----
__global__ __launch_bounds__(256) void k_conv1(const float* __restrict__ f,
                                               const float* __restrict__ w1r,
                                               const float* __restrict__ b1,
                                               float* __restrict__ xo,
                                               float* __restrict__ xt,
                                               unsigned* __restrict__ scal,
                                               unsigned long long* __restrict__ sel) {
    __shared__ __align__(16) float sI[2][2880];   // 2 x 11,520 B
    int tid = threadIdx.x;
    int fb = blockIdx.x + 9 * (blockIdx.y + 25 * blockIdx.z);
    // workspace init: 64 scal words + 32768 sel-words
    {
        int g = fb * 256 + tid;
        if (g < 64) scal[g] = 0u;
        else if (g < 32832) ((unsigned*)sel)[g - 64] = 0xFFFFFFFFu;
    }
    int lane = tid & 63;
    int wgl = __builtin_amdgcn_readfirstlane(tid >> 6);
    int xg = lane & 7;
    int yg = lane >> 3;
    int X0 = blockIdx.x * 32;
    int Y0 = blockIdx.y * 8;
    int wg = blockIdx.z * 4 + wgl;   // oc-group of 8, wave-uniform
    int y = Y0 + yg;
    int xbase = X0 + xg * 4;

    int off[11]; int lds[11]; bool ok[11];
#pragma unroll
    for (int it = 0; it < 11; it++) {
        int l = tid + it * 256;
        int ci = l / 340; int r = l - ci * 340; int ry = r / 34; int rx = r - ry * 34;
        int gx = X0 - 1 + rx, gy = Y0 - 1 + ry;
        ok[it] = (l < CHUNK_W) && gx >= 0 && gx < W_ && gy >= 0 && gy < H_;
        off[it] = ci * HW + gy * W_ + gx;
        lds[it] = (ci * 10 + ry) * 36 + rx;
    }
    float rbuf[11];
#pragma unroll
    for (int it = 0; it < 11; it++)
        rbuf[it] = ok[it] ? f[off[it]] : 0.f;
#pragma unroll
    for (int it = 0; it < 11; it++)
        if (tid + it * 256 < CHUNK_W) sI[0][lds[it]] = rbuf[it];
    __syncthreads();

    float acc[8][4];
#pragma unroll
    for (int o = 0; o < 8; o++)
#pragma unroll
        for (int i = 0; i < 4; i++) acc[o][i] = 0.f;

    const float* wbase = w1r + (size_t)wg * (256 * 72);  // repacked, wave-uniform

    int cur = 0;
    for (int ic0 = 0; ic0 < 256; ic0 += 8) {
        if (ic0 < 248) {
            const float* fn = f + (size_t)(ic0 + 8) * HW;
#pragma unroll
            for (int it = 0; it < 11; it++)
                rbuf[it] = ok[it] ? fn[off[it]] : 0.f;
        }
        const float* sbuf = sI[cur];
        for (int ci = 0; ci < 8; ci++) {
            const float* wci = wbase + (ic0 + ci) * 72;   // 9 taps x 8 oc, contiguous
#pragma unroll
            for (int ky = 0; ky < 3; ky++) {
                const float* irow = &sbuf[(ci * 10 + yg + ky) * 36 + xg * 4];
                float4 va = *(const float4*)irow;
                float2 vb = *(const float2*)(irow + 4);
                float in[6] = {va.x, va.y, va.z, va.w, vb.x, vb.y};
#pragma unroll
                for (int kx = 0; kx < 3; kx++) {
                    const float* w8 = wci + (ky * 3 + kx) * 8;
#pragma unroll
                    for (int o = 0; o < 8; o++) {
                        float w = w8[o];   // s_load from contiguous 32B group
#pragma unroll
                        for (int i = 0; i < 4; i++)
                            acc[o][i] = fmaf(w, in[i + kx], acc[o][i]);
                    }
                }
            }
        }
        if (ic0 < 248) {
#pragma unroll
            for (int it = 0; it < 11; it++)
                if (tid + it * 256 < CHUNK_W) sI[cur ^ 1][lds[it]] = rbuf[it];
        }
        __syncthreads();
        cur ^= 1;
    }
    // epilogue: same per-element ops/order (bias add, relu)
    float vout[8][4];
#pragma unroll
    for (int o = 0; o < 8; o++) {
        float bv = b1[wg * 8 + o];
#pragma unroll
        for (int i = 0; i < 4; i++)
            vout[o][i] = fmaxf(acc[o][i] + bv, 0.f);
    }
#pragma unroll
    for (int o = 0; o < 8; o++) {
        int oc = wg * 8 + o;
        float* orow = xo + (size_t)oc * HW + y * W_ + xbase;
        if (xbase + 3 < W_) {
            *(float4*)orow = make_float4(vout[o][0], vout[o][1], vout[o][2], vout[o][3]);
        } else {
            for (int i = 0; i < 4; i++)
                if (xbase + i < W_) orow[i] = vout[o][i];
        }
    }
    if (xt) {   // transposed copy (identical values, different address)
#pragma unroll
        for (int i = 0; i < 4; i++) {
            if (xbase + i < W_) {
                size_t px = (size_t)(y * W_ + xbase + i);
                *(float4*)&xt[px * 256 + wg * 8] =
                    make_float4(vout[0][i], vout[1][i], vout[2][i], vout[3][i]);
                *(float4*)&xt[px * 256 + wg * 8 + 4] =
                    make_float4(vout[4][i], vout[5][i], vout[6][i], vout[7][i]);
            }
        }
    }
}

// ---- 1x1 cls conv -> conf[p*9+a], fused radix histogram.
// ILP-8 prefetch (R9); 16-way segmented histogram (R10 proved the axis). ----
__global__ __launch_bounds__(256) void k_cls(const float* __restrict__ x,
                                             const float* __restrict__ wcr,
                                             const float* __restrict__ bc,
                                             float* __restrict__ conf,
                                             unsigned* __restrict__ histc) {
    int p = blockIdx.x * 256 + threadIdx.x;
    if (p >= HW) return;
    unsigned* myh = histc + (blockIdx.x & (NSEG - 1)) * 65536;
    float acc[9];
#pragma unroll
    for (int a = 0; a < 9; a++) acc[a] = 0.f;
    for (int c0 = 0; c0 < 256; c0 += 8) {
        float xv8[8];
#pragma unroll
        for (int j = 0; j < 8; j++)
            xv8[j] = x[(c0 + j) * HW + p];     // 8 independent loads in flight
#pragma unroll
        for (int j = 0; j < 8; j++) {
            const float* wp = wcr + (c0 + j) * 9;  // uniform -> s_load
#pragma unroll
            for (int a = 0; a < 9; a++) acc[a] = fmaf(wp[a], xv8[j], acc[a]);
        }
    }
#pragma unroll
    for (int a = 0; a < 9; a++) {
        float v = acc[a] + bc[a];
        conf[p * 9 + a] = v;
        atomicAdd(&myh[fkey(v) >> 16], 1u);
    }
}

// ---- descending scan over the segment-summed 65536-bin histogram. ----
__global__ __launch_bounds__(1024) void k_scan(const unsigned* __restrict__ histc,
                                               unsigned* scal) {
    __shared__ unsigned ssum[1024];
    int t = threadIdx.x;
    int base = 65535 - t * 64;
    unsigned s = 0;
    for (int seg = 0; seg < NSEG; seg++) {
        const uint4* hp = (const uint4*)(histc + seg * 65536 + (base - 63));
#pragma unroll
        for (int k = 0; k < 16; k++) { uint4 v = hp[k]; s += v.x + v.y + v.z + v.w; }
    }
    ssum[t] = s;
    __syncthreads();
    for (int off = 1; off < 1024; off <<= 1) {
        unsigned v = (t >= off) ? ssum[t - off] : 0u;
        __syncthreads();
        ssum[t] += v;
        __syncthreads();
    }
    unsigned incl = ssum[t], excl = incl - s;
    if (excl < 6000u && 6000u <= incl) {
        unsigned run = excl;
        bool found = false;
        for (int pass = 0; pass < 2 && !found; pass++) {
            unsigned c32[32];
#pragma unroll
            for (int j = 0; j < 32; j++) {
                int idx = base - (pass * 32 + j);
                unsigned cj = 0;
#pragma unroll
                for (int seg = 0; seg < NSEG; seg++) cj += histc[seg * 65536 + idx];
                c32[j] = cj;
            }
            for (int j = 0; j < 32; j++) {
                if (run + c32[j] >= 6000u) {
                    scal[0] = (unsigned)(base - (pass * 32 + j));
                    scal[1] = run;
                    found = true;
                    break;
                }
                run += c32[j];
            }
        }
    }
}

// ---- single-pass gather: block-aggregated atomics (R10, proven -66us). ----
__global__ __launch_bounds__(256) void k_gather(const float* __restrict__ conf,
                                                unsigned* scal, unsigned long long* sel) {
    __shared__ unsigned lcA, lcB, bA, bB;
    int n = blockIdx.x * 256 + threadIdx.x;
    bool inr = n < NANCH;
    if (threadIdx.x == 0) { lcA = 0u; lcB = 0u; }
    __syncthreads();
    unsigned B1 = scal[0], cnt1 = scal[1];
    unsigned key = 0, off = 0;
    int cls = 0;
    if (inr) {
        key = fkey(conf[n]);
        unsigned pre = key >> 16;
        if (pre > B1)       { cls = 1; off = atomicAdd(&lcA, 1u); }
        else if (pre == B1) { cls = 2; off = atomicAdd(&lcB, 1u); }
    }
    __syncthreads();
    if (threadIdx.x == 0) {
        bA = lcA ? atomicAdd(&scal[4], lcA) : 0u;
        bB = lcB ? atomicAdd(&scal[36], lcB) : 0u;
    }
    __syncthreads();
    if (cls) {
        unsigned long long kk = ((unsigned long long)(~key) << 32) | (unsigned)n;  // smaller = better
        if (cls == 1) {
            sel[bA + off] = kk;                  // [0, cnt1) by construction
        } else {
            unsigned pos = cnt1 + bB + off;
            if (pos < SELCAP) sel[pos] = kk;
        }
    }
}

// ---- exact rank by pairwise comparison over [0, SELCAP) with early-out ----
__global__ __launch_bounds__(256) void k_rank(const unsigned* __restrict__ scal,
                                              const unsigned long long* __restrict__ sel,
                                              unsigned* __restrict__ topidx) {
    __shared__ unsigned long long tile[2048];
    unsigned filled = scal[1] + scal[36];
    if (filled > SELCAP) filled = SELCAP;
    int i = blockIdx.x * 256 + threadIdx.x;
    unsigned long long mykey = sel[i];
    int rank = 0;
    for (int t0 = 0; t0 < SELCAP; t0 += 2048) {
        if (t0 >= (int)filled) break;   // uniform across block
        __syncthreads();
        for (int l = threadIdx.x; l < 2048; l += 256)
            tile[l] = sel[t0 + l];
        __syncthreads();
        for (int l = 0; l < 2048; l += 4) {
            ulonglong2 p = *(const ulonglong2*)&tile[l];
            ulonglong2 q = *(const ulonglong2*)&tile[l + 2];
            rank += (p.x < mykey) + (p.y < mykey) + (q.x < mykey) + (q.y < mykey);
        }
    }
    if (i < (int)filled && rank < PRE_N)
        topidx[rank] = (unsigned)(mykey & 0xFFFFFFFFull);
}

// ---- per-proposal: reg conv (4 channels), anchor, decode, clip, valid. ----
__global__ __launch_bounds__(256) void k_prop(const float* __restrict__ x,
                                              const float* __restrict__ xt,
                                              const float* __restrict__ wreg,
                                              const float* __restrict__ breg,
                                              const unsigned* __restrict__ topidx,
                                              const int* __restrict__ imh, const int* __restrict__ imw,
                                              float* __restrict__ boxes, int* __restrict__ valid) {
    int r = blockIdx.x * 4 + (threadIdx.x >> 6);   // 1500 blocks x 4 waves = 6000
    int lane = threadIdx.x & 63;
    unsigned n = topidx[r];
    int a = (int)(n % 9u); int p = (int)(n / 9u);
    const float* wr = wreg + (4 * a) * 256;
    float xv4[4], w0[4], w1[4], w2[4], w3[4];
    if (xt) {
        const float* xp = xt + (size_t)p * 256;
#pragma unroll
        for (int j = 0; j < 4; j++) {
            int c = lane + 64 * j;
            xv4[j] = xp[c];
            w0[j] = wr[c]; w1[j] = wr[256 + c]; w2[j] = wr[512 + c]; w3[j] = wr[768 + c];
        }
    } else {
#pragma unroll
        for (int j = 0; j < 4; j++) {
            int c = lane + 64 * j;
            xv4[j] = x[c * HW + p];
            w0[j] = wr[c]; w1[j] = wr[256 + c]; w2[j] = wr[512 + c]; w3[j] = wr[768 + c];
        }
    }
    float s0 = 0, s1 = 0, s2 = 0, s3 = 0;
#pragma unroll
    for (int j = 0; j < 4; j++) {
        s0 = fmaf(w0[j], xv4[j], s0);
        s1 = fmaf(w1[j], xv4[j], s1);
        s2 = fmaf(w2[j], xv4[j], s2);
        s3 = fmaf(w3[j], xv4[j], s3);
    }
#pragma unroll
    for (int off = 32; off >= 1; off >>= 1) {
        s0 += __shfl_down(s0, off);
        s1 += __shfl_down(s1, off);
        s2 += __shfl_down(s2, off);
        s3 += __shfl_down(s3, off);
    }
    if (lane == 0) {
        float dx = s0 + breg[4 * a], dy = s1 + breg[4 * a + 1];
        float dw = s2 + breg[4 * a + 2], dh = s3 + breg[4 * a + 3];
        int wi = p % W_, hi = p / W_;
        const double SC[3] = {32.0, 64.0, 128.0};
        const double RT[3] = {0.5, 1.0, 2.0};
        double sd = SC[a / 3], rd = RT[a % 3];
        double wb = sd * sqrt(1.0 / rd), hb = sd * sqrt(rd);
        float bx1 = (float)(-wb * 0.5), by1 = (float)(-hb * 0.5);
        float bx2 = (float)(wb * 0.5),  by2 = (float)(hb * 0.5);
        float cxs = ((float)wi + 0.5f) * 4.0f, cys = ((float)hi + 0.5f) * 4.0f;
        float x1a = cxs + bx1, y1a = cys + by1, x2a = cxs + bx2, y2a = cys + by2;
        float wa = x2a - x1a, ha = y2a - y1a;
        float cxa = x1a + 0.5f * wa, cya = y1a + 0.5f * ha;
        float cx = dx * wa + cxa, cy = dy * ha + cya;
        float ww = expf(dw) * wa, hh = expf(dh) * ha;
        float X1 = cx - 0.5f * ww, Y1 = cy - 0.5f * hh;
        float X2 = cx + 0.5f * ww, Y2 = cy + 0.5f * hh;
        float Wf = (float)(*imw), Hf = (float)(*imh);
        X1 = fminf(fmaxf(X1, 0.f), Wf); Y1 = fminf(fmaxf(Y1, 0.f), Hf);
        X2 = fminf(fmaxf(X2, 0.f), Wf); Y2 = fminf(fmaxf(Y2, 0.f), Hf);
        boxes[4 * r] = X1; boxes[4 * r + 1] = Y1; boxes[4 * r + 2] = X2; boxes[4 * r + 3] = Y2;
        valid[r] = ((X2 - X1) >= 1.0f && (Y2 - Y1) >= 1.0f) ? 1 : 0;
    }
}

// ---- NMS IoU bitmask. Lower-triangle blocks skipped (never read). ----
__global__ __launch_bounds__(256) void k_mask(const float* __restrict__ boxes,
                                              unsigned long long* __restrict__ mask) {
    __shared__ float jb[256];
    int jw = blockIdx.x;
    if (jw * 64 + 63 < (int)blockIdx.y * 256) return;   // never-read region
    int i = blockIdx.y * 256 + threadIdx.x;
    {
        int idx = jw * 256 + threadIdx.x;
        jb[threadIdx.x] = (idx < PRE_N * 4) ? boxes[idx] : 0.f;
    }
    __syncthreads();
    if (i >= PRE_N) return;
    float4 ab = *(const float4*)&boxes[4 * i];
    float ax1 = ab.x, ay1 = ab.y, ax2 = ab.z, ay2 = ab.w;
    float aarea = (ax2 - ax1) * (ay2 - ay1);
    unsigned long long m = 0;
    int jbase = jw * 64;
    for (int b = 0; b < 64; b++) {
        int j = jbase + b;
        if (j <= i || j >= PRE_N) continue;
        float bx1 = jb[4 * b], by1 = jb[4 * b + 1], bx2 = jb[4 * b + 2], by2 = jb[4 * b + 3];
        float barea = (bx2 - bx1) * (by2 - by1);
        float xx1 = fmaxf(ax1, bx1), yy1 = fmaxf(ay1, by1);
        float xx2 = fminf(ax2, bx2), yy2 = fminf(ay2, by2);
        float w = fmaxf(xx2 - xx1, 0.f), h = fmaxf(yy2 - yy1, 0.f);
        float inter = w * h;
        float iou = inter / (aarea + barea - inter + 1e-9f);
        if (iou > 0.7f) m |= (1ull << b);
    }
    mask[(size_t)i * NWORDS + jw] = m;
}

// ---- greedy scan: serial walk on wave 0 via register diag rows + shfl ----
__global__ __launch_bounds__(256) void k_scan_nms(const unsigned long long* __restrict__ mask,
                                                  const int* __restrict__ valid,
                                                  const float* __restrict__ boxes,
                                                  float* __restrict__ out) {
    __shared__ unsigned long long diag[NWORDS][64];   // 48,128 B
    __shared__ unsigned long long removed[NWORDS];
    __shared__ unsigned long long validw[NWORDS];
    __shared__ int keepList[POST_N];
    __shared__ int cnt;
    __shared__ unsigned long long keptbits;
    int t = threadIdx.x;
    if (t < NWORDS) { removed[t] = 0ull; validw[t] = 0ull; }
    if (t == 0) cnt = 0;
    __syncthreads();
    for (int l = t; l < NWORDS * 64; l += 256) {
        int w = l >> 6, b = l & 63;
        int i = w * 64 + b;
        diag[w][b] = (i < PRE_N) ? mask[(size_t)i * NWORDS + w] : 0ull;
    }
    for (int i = t; i < PRE_N; i += 256)
        if (valid[i]) atomicOr(&validw[i >> 6], 1ull << (i & 63));
    __syncthreads();
    for (int w = 0; w < NWORDS; w++) {
        unsigned long long candw = validw[w] & ~removed[w];
        if (!candw) continue;
        if (t < 64) {
            unsigned long long mydiag = diag[w][t];   // lane t owns row (w*64+t)'s word w
            unsigned long long cand = candw;
            unsigned long long kb = 0ull;
            int c = cnt;
            while (cand && c < POST_N) {
                int b = __ffsll((unsigned long long)cand) - 1;
                unsigned long long sup = __shfl(mydiag, b);   // register, ~5 cyc
                if (t == 0) keepList[c] = w * 64 + b;
                c++;
                kb |= 1ull << b;
                cand &= ~(1ull << b);
                cand &= ~sup;
            }
            if (t == 0) { cnt = c; keptbits = kb; }
        }
        __syncthreads();
        if (cnt >= POST_N) break;
        unsigned long long kb = keptbits;
        if (kb) {
            for (int w2 = w + 1 + t; w2 < NWORDS; w2 += 256) {
                unsigned long long acc2 = removed[w2];
                unsigned long long tt = kb;
                while (tt) {
                    int b = __ffsll((unsigned long long)tt) - 1;
                    tt &= tt - 1;
                    acc2 |= mask[(size_t)(w * 64 + b) * NWORDS + w2];
                }
                removed[w2] = acc2;
            }
        }
        __syncthreads();
    }
    __syncthreads();
    int c = cnt;
    for (int e = t; e < POST_N * 4; e += 256) {
        int r = e >> 2;
        out[e] = (r < c) ? boxes[4 * keepList[r] + (e & 3)] : 0.f;
    }
}

extern "C" void kernel_launch(void* const* d_in, const int* in_sizes, int n_in,
                              void* d_out, int out_size, void* d_ws, size_t ws_size,
                              hipStream_t stream) {
    const float* feature = (const float*)d_in[0];
    const float* w1   = (const float*)d_in[1];
    const float* b1   = (const float*)d_in[2];
    const float* wcls = (const float*)d_in[3];
    const float* bcls = (const float*)d_in[4];
    const float* wreg = (const float*)d_in[5];
    const float* breg = (const float*)d_in[6];
    const int* imh = (const int*)d_in[7];
    const int* imw = (const int*)d_in[8];

    char* ws = (char*)d_ws;
    float* xbuf  = (float*)(ws + X_OFF);
    float* conf  = (float*)(ws + CONF_OFF);
    unsigned* scal  = (unsigned*)(ws + SCAL_OFF);
    unsigned long long* sel = (unsigned long long*)(ws + SEL_OFF);
    unsigned* topidx = (unsigned*)(ws + TOPIDX_OFF);
    float* boxes = (float*)(ws + BOXES_OFF);
    int* valid   = (int*)(ws + VALID_OFF);
    unsigned long long* mask = (unsigned long long*)(ws + MASK_OFF);
    float* w1r = (float*)(ws + MASK_OFF);          // dead after k_conv1; overwritten by k_mask
    unsigned* histc = (unsigned*)(ws + HISTC_OFF); // 16 segments; dead after k_scan
    float* wcr = (float*)(ws + WCR_OFF);
    float* xt  = (ws_size >= WS_NEED_XT) ? (float*)(ws + XT_OFF) : (float*)0;
    float* outF = (float*)d_out;

    hipLaunchKernelGGL(k_repack, dim3(2304), dim3(256), 0, stream, w1, w1r, histc, wcls, wcr);
    hipLaunchKernelGGL(k_conv1,  dim3(9, 25, 8), dim3(256), 0, stream,
                       feature, w1r, b1, xbuf, xt, scal, sel);
    hipLaunchKernelGGL(k_cls,    dim3(213),  dim3(256), 0, stream, xbuf, wcr, bcls, conf, histc);
    hipLaunchKernelGGL(k_scan,   dim3(1),    dim3(1024), 0, stream, histc, scal);
    hipLaunchKernelGGL(k_gather, dim3(1913), dim3(256), 0, stream, conf, scal, sel);
    hipLaunchKernelGGL(k_rank,   dim3(64),   dim3(256), 0, stream, scal, sel, topidx);
    hipLaunchKernelGGL(k_prop,   dim3(1500), dim3(256), 0, stream, xbuf, xt, wreg, breg, topidx, imh, imw, boxes, valid);
    hipLaunchKernelGGL(k_mask,   dim3(NWORDS, 24), dim3(256), 0, stream, boxes, mask);
    hipLaunchKernelGGL(k_scan_nms, dim3(1), dim3(256), 0, stream, mask, valid, boxes, outF);
}

// Round 13
// 1460.351 us; speedup vs baseline: 1.1664x; 1.0440x over previous
//
#include <hip/hip_runtime.h>
#include <hip/hip_bf16.h>
#include <math.h>

#define H_ 200
#define W_ 272
#define C_ 256
#define HW 54400
#define NANCH 489600
#define PRE_N 6000
#define POST_N 1000
#define NWORDS 94    // ceil(6000/64)
#define CHUNK_W 2720 // 8 ic * 10 rows * 34 cols halo
#define SELCAP 16384
#define NSEG 8       // histogram privatization copies (R10-proven; 16 regressed in R12)

// ---- workspace layout (bytes) ----
#define X_OFF       0ull                 // 256*54400*4 = 55,705,600
#define CONF_OFF    55705600ull          // 489600*4   =  1,958,400
#define HIST1_OFF   57664000ull          // 65536*4 (unused since R10)
#define SEL_OFF     57926144ull          // 16384*8    =    131,072
#define SCAL_OFF    58188288ull          // 64*4
#define TOPIDX_OFF  58254080ull          // 6000*4
#define BOXES_OFF   58278080ull          // 6000*4*4
#define VALID_OFF   58374080ull          // 6000*4
#define MASK_OFF    58398080ull          // 6000*94*8 = 4,512,000 (w1r + histc live here pre-k_mask)
#define HISTC_OFF   60757376ull          // MASK_OFF + 2,359,296 (w1r); 8*65536*4 = 2,097,152
#define WCR_OFF     65269376ull          // 9*256*4
#define XT_OFF      65278592ull          // optional: 54400*256*4 = 55,705,600 (transposed x)
#define WS_NEED_XT  (XT_OFF + 55705600ull)

__device__ __forceinline__ unsigned fkey(float fv) {
    unsigned u = __float_as_uint(fv);
    return (u & 0x80000000u) ? ~u : (u | 0x80000000u);  // monotone: bigger float -> bigger key
}

// ---- weight repack + histogram-segment zeroing (R10-exact). ----
__global__ __launch_bounds__(256) void k_repack(const float* __restrict__ w1,
                                                float* __restrict__ w1r,
                                                unsigned* __restrict__ histc) {
    int d = blockIdx.x * 256 + threadIdx.x;   // 589,824 total
    if (d < NSEG * 65536) histc[d] = 0u;
    int o = d & 7;
    int q = d >> 3;            // icg*9 + t
    int t = q % 9;
    int icg = q / 9;           // wg8*256 + ic
    int wg8 = icg >> 8, ic = icg & 255;
    w1r[d] = w1[((size_t)(wg8 * 8 + o) * 256 + ic) * 9 + t];
}

// ---- 3x3 conv + bias + relu. R2-proven structure (818us): 32x8 tile,
// 8 oc x 4 px/lane, 8-ic double buffer, 1800 blocks, one barrier/chunk,
// b128/b64 LDS reads, repacked contiguous uniform weights. DO NOT change
// the main loop (R1/R3/R4/R6 regressed); no fusion/fences (R11 regressed).
// Epilogue also writes transposed xt[p*256+oc] (R8, ~free). ----
__global__ __launch_bounds__(256) void k_conv1(const float* __restrict__ f,
                                               const float* __restrict__ w1r,
                                               const float* __restrict__ b1,
                                               float* __restrict__ xo,
                                               float* __restrict__ xt,
                                               unsigned* __restrict__ scal,
                                               unsigned long long* __restrict__ sel,
                                               const float* __restrict__ wcls,
                                               float* __restrict__ wcr) {
    __shared__ __align__(16) float sI[2][2880];   // 2 x 11,520 B
    int tid = threadIdx.x;
    int fb = blockIdx.x + 9 * (blockIdx.y + 25 * blockIdx.z);
    // workspace init: 64 scal words + 32768 sel-words (hist zeroing in k_repack)
    {
        int g = fb * 256 + tid;
        if (g < 64) scal[g] = 0u;
        else if (g < 32832) ((unsigned*)sel)[g - 64] = 0xFFFFFFFFu;
    }
    if (fb == 0) {
        for (int e = tid; e < 2304; e += 256) {
            int a = e / 256, c = e % 256;
            wcr[c * 9 + a] = wcls[e];
        }
    }
    int lane = tid & 63;
    int wgl = __builtin_amdgcn_readfirstlane(tid >> 6);
    int xg = lane & 7;
    int yg = lane >> 3;
    int X0 = blockIdx.x * 32;
    int Y0 = blockIdx.y * 8;
    int wg = blockIdx.z * 4 + wgl;   // oc-group of 8, wave-uniform
    int y = Y0 + yg;
    int xbase = X0 + xg * 4;

    int off[11]; int lds[11]; bool ok[11];
#pragma unroll
    for (int it = 0; it < 11; it++) {
        int l = tid + it * 256;
        int ci = l / 340; int r = l - ci * 340; int ry = r / 34; int rx = r - ry * 34;
        int gx = X0 - 1 + rx, gy = Y0 - 1 + ry;
        ok[it] = (l < CHUNK_W) && gx >= 0 && gx < W_ && gy >= 0 && gy < H_;
        off[it] = ci * HW + gy * W_ + gx;
        lds[it] = (ci * 10 + ry) * 36 + rx;
    }
    float rbuf[11];
#pragma unroll
    for (int it = 0; it < 11; it++)
        rbuf[it] = ok[it] ? f[off[it]] : 0.f;
#pragma unroll
    for (int it = 0; it < 11; it++)
        if (tid + it * 256 < CHUNK_W) sI[0][lds[it]] = rbuf[it];
    __syncthreads();

    float acc[8][4];
#pragma unroll
    for (int o = 0; o < 8; o++)
#pragma unroll
        for (int i = 0; i < 4; i++) acc[o][i] = 0.f;

    const float* wbase = w1r + (size_t)wg * (256 * 72);  // repacked, wave-uniform

    int cur = 0;
    for (int ic0 = 0; ic0 < 256; ic0 += 8) {
        if (ic0 < 248) {
            const float* fn = f + (size_t)(ic0 + 8) * HW;
#pragma unroll
            for (int it = 0; it < 11; it++)
                rbuf[it] = ok[it] ? fn[off[it]] : 0.f;
        }
        const float* sbuf = sI[cur];
        for (int ci = 0; ci < 8; ci++) {
            const float* wci = wbase + (ic0 + ci) * 72;   // 9 taps x 8 oc, contiguous
#pragma unroll
            for (int ky = 0; ky < 3; ky++) {
                const float* irow = &sbuf[(ci * 10 + yg + ky) * 36 + xg * 4];
                float4 va = *(const float4*)irow;
                float2 vb = *(const float2*)(irow + 4);
                float in[6] = {va.x, va.y, va.z, va.w, vb.x, vb.y};
#pragma unroll
                for (int kx = 0; kx < 3; kx++) {
                    const float* w8 = wci + (ky * 3 + kx) * 8;
#pragma unroll
                    for (int o = 0; o < 8; o++) {
                        float w = w8[o];   // s_load from contiguous 32B group
#pragma unroll
                        for (int i = 0; i < 4; i++)
                            acc[o][i] = fmaf(w, in[i + kx], acc[o][i]);
                    }
                }
            }
        }
        if (ic0 < 248) {
#pragma unroll
            for (int it = 0; it < 11; it++)
                if (tid + it * 256 < CHUNK_W) sI[cur ^ 1][lds[it]] = rbuf[it];
        }
        __syncthreads();
        cur ^= 1;
    }
    // epilogue: same per-element ops/order as before (bias add, relu)
    float vout[8][4];
#pragma unroll
    for (int o = 0; o < 8; o++) {
        float bv = b1[wg * 8 + o];
#pragma unroll
        for (int i = 0; i < 4; i++)
            vout[o][i] = fmaxf(acc[o][i] + bv, 0.f);
    }
#pragma unroll
    for (int o = 0; o < 8; o++) {
        int oc = wg * 8 + o;
        float* orow = xo + (size_t)oc * HW + y * W_ + xbase;
        if (xbase + 3 < W_) {
            *(float4*)orow = make_float4(vout[o][0], vout[o][1], vout[o][2], vout[o][3]);
        } else {
            for (int i = 0; i < 4; i++)
                if (xbase + i < W_) orow[i] = vout[o][i];
        }
    }
    if (xt) {   // transposed copy (identical values, different address)
#pragma unroll
        for (int i = 0; i < 4; i++) {
            if (xbase + i < W_) {
                size_t px = (size_t)(y * W_ + xbase + i);
                *(float4*)&xt[px * 256 + wg * 8] =
                    make_float4(vout[0][i], vout[1][i], vout[2][i], vout[3][i]);
                *(float4*)&xt[px * 256 + wg * 8 + 4] =
                    make_float4(vout[4][i], vout[5][i], vout[6][i], vout[7][i]);
            }
        }
    }
}

// ---- 1x1 cls conv -> conf[p*9+a], fused radix histogram.
// ILP-8 prefetch (R9); 8-way segmented histogram (R10, proven -66us). ----
__global__ __launch_bounds__(256) void k_cls(const float* __restrict__ x,
                                             const float* __restrict__ wcr,
                                             const float* __restrict__ bc,
                                             float* __restrict__ conf,
                                             unsigned* __restrict__ histc) {
    int p = blockIdx.x * 256 + threadIdx.x;
    if (p >= HW) return;
    unsigned* myh = histc + (blockIdx.x & (NSEG - 1)) * 65536;
    float acc[9];
#pragma unroll
    for (int a = 0; a < 9; a++) acc[a] = 0.f;
    for (int c0 = 0; c0 < 256; c0 += 8) {
        float xv8[8];
#pragma unroll
        for (int j = 0; j < 8; j++)
            xv8[j] = x[(c0 + j) * HW + p];     // 8 independent loads in flight
#pragma unroll
        for (int j = 0; j < 8; j++) {
            const float* wp = wcr + (c0 + j) * 9;  // uniform -> s_load
#pragma unroll
            for (int a = 0; a < 9; a++) acc[a] = fmaf(wp[a], xv8[j], acc[a]);
        }
    }
#pragma unroll
    for (int a = 0; a < 9; a++) {
        float v = acc[a] + bc[a];
        conf[p * 9 + a] = v;
        atomicAdd(&myh[fkey(v) >> 16], 1u);
    }
}

// ---- descending scan over the segment-summed 65536-bin histogram. ----
__global__ __launch_bounds__(1024) void k_scan(const unsigned* __restrict__ histc,
                                               unsigned* scal) {
    __shared__ unsigned ssum[1024];
    int t = threadIdx.x;
    int base = 65535 - t * 64;
    unsigned s = 0;
    for (int seg = 0; seg < NSEG; seg++) {
        const uint4* hp = (const uint4*)(histc + seg * 65536 + (base - 63));
#pragma unroll
        for (int k = 0; k < 16; k++) { uint4 v = hp[k]; s += v.x + v.y + v.z + v.w; }
    }
    ssum[t] = s;
    __syncthreads();
    for (int off = 1; off < 1024; off <<= 1) {
        unsigned v = (t >= off) ? ssum[t - off] : 0u;
        __syncthreads();
        ssum[t] += v;
        __syncthreads();
    }
    unsigned incl = ssum[t], excl = incl - s;
    if (excl < 6000u && 6000u <= incl) {
        unsigned run = excl;
        bool found = false;
        for (int pass = 0; pass < 2 && !found; pass++) {
            unsigned c32[32];
#pragma unroll
            for (int j = 0; j < 32; j++) {
                int idx = base - (pass * 32 + j);
                unsigned cj = 0;
#pragma unroll
                for (int seg = 0; seg < NSEG; seg++) cj += histc[seg * 65536 + idx];
                c32[j] = cj;
            }
            for (int j = 0; j < 32; j++) {
                if (run + c32[j] >= 6000u) {
                    scal[0] = (unsigned)(base - (pass * 32 + j));
                    scal[1] = run;
                    found = true;
                    break;
                }
                run += c32[j];
            }
        }
    }
}

// ---- single-pass gather: block-aggregated atomics (R10, proven -66us). ----
__global__ __launch_bounds__(256) void k_gather(const float* __restrict__ conf,
                                                unsigned* scal, unsigned long long* sel) {
    __shared__ unsigned lcA, lcB, bA, bB;
    int n = blockIdx.x * 256 + threadIdx.x;
    bool inr = n < NANCH;
    if (threadIdx.x == 0) { lcA = 0u; lcB = 0u; }
    __syncthreads();
    unsigned B1 = scal[0], cnt1 = scal[1];
    unsigned key = 0, off = 0;
    int cls = 0;
    if (inr) {
        key = fkey(conf[n]);
        unsigned pre = key >> 16;
        if (pre > B1)       { cls = 1; off = atomicAdd(&lcA, 1u); }
        else if (pre == B1) { cls = 2; off = atomicAdd(&lcB, 1u); }
    }
    __syncthreads();
    if (threadIdx.x == 0) {
        bA = lcA ? atomicAdd(&scal[4], lcA) : 0u;
        bB = lcB ? atomicAdd(&scal[36], lcB) : 0u;
    }
    __syncthreads();
    if (cls) {
        unsigned long long kk = ((unsigned long long)(~key) << 32) | (unsigned)n;  // smaller = better
        if (cls == 1) {
            sel[bA + off] = kk;                  // [0, cnt1) by construction
        } else {
            unsigned pos = cnt1 + bB + off;
            if (pos < SELCAP) sel[pos] = kk;
        }
    }
}

// ---- exact rank by pairwise comparison over [0, SELCAP) with early-out ----
__global__ __launch_bounds__(256) void k_rank(const unsigned* __restrict__ scal,
                                              const unsigned long long* __restrict__ sel,
                                              unsigned* __restrict__ topidx) {
    __shared__ unsigned long long tile[2048];
    unsigned filled = scal[1] + scal[36];
    if (filled > SELCAP) filled = SELCAP;
    int i = blockIdx.x * 256 + threadIdx.x;
    unsigned long long mykey = sel[i];
    int rank = 0;
    for (int t0 = 0; t0 < SELCAP; t0 += 2048) {
        if (t0 >= (int)filled) break;   // uniform across block
        __syncthreads();
        for (int l = threadIdx.x; l < 2048; l += 256)
            tile[l] = sel[t0 + l];
        __syncthreads();
        for (int l = 0; l < 2048; l += 4) {
            ulonglong2 p = *(const ulonglong2*)&tile[l];
            ulonglong2 q = *(const ulonglong2*)&tile[l + 2];
            rank += (p.x < mykey) + (p.y < mykey) + (q.x < mykey) + (q.y < mykey);
        }
    }
    if (i < (int)filled && rank < PRE_N)
        topidx[rank] = (unsigned)(mykey & 0xFFFFFFFFull);
}

// ---- per-proposal: reg conv (4 channels), anchor, decode, clip, valid. ----
__global__ __launch_bounds__(256) void k_prop(const float* __restrict__ x,
                                              const float* __restrict__ xt,
                                              const float* __restrict__ wreg,
                                              const float* __restrict__ breg,
                                              const unsigned* __restrict__ topidx,
                                              const int* __restrict__ imh, const int* __restrict__ imw,
                                              float* __restrict__ boxes, int* __restrict__ valid) {
    int r = blockIdx.x * 4 + (threadIdx.x >> 6);   // 1500 blocks x 4 waves = 6000
    int lane = threadIdx.x & 63;
    unsigned n = topidx[r];
    int a = (int)(n % 9u); int p = (int)(n / 9u);
    const float* wr = wreg + (4 * a) * 256;
    float xv4[4], w0[4], w1[4], w2[4], w3[4];
    if (xt) {
        const float* xp = xt + (size_t)p * 256;
#pragma unroll
        for (int j = 0; j < 4; j++) {
            int c = lane + 64 * j;
            xv4[j] = xp[c];
            w0[j] = wr[c]; w1[j] = wr[256 + c]; w2[j] = wr[512 + c]; w3[j] = wr[768 + c];
        }
    } else {
#pragma unroll
        for (int j = 0; j < 4; j++) {
            int c = lane + 64 * j;
            xv4[j] = x[c * HW + p];
            w0[j] = wr[c]; w1[j] = wr[256 + c]; w2[j] = wr[512 + c]; w3[j] = wr[768 + c];
        }
    }
    float s0 = 0, s1 = 0, s2 = 0, s3 = 0;
#pragma unroll
    for (int j = 0; j < 4; j++) {
        s0 = fmaf(w0[j], xv4[j], s0);
        s1 = fmaf(w1[j], xv4[j], s1);
        s2 = fmaf(w2[j], xv4[j], s2);
        s3 = fmaf(w3[j], xv4[j], s3);
    }
#pragma unroll
    for (int off = 32; off >= 1; off >>= 1) {
        s0 += __shfl_down(s0, off);
        s1 += __shfl_down(s1, off);
        s2 += __shfl_down(s2, off);
        s3 += __shfl_down(s3, off);
    }
    if (lane == 0) {
        float dx = s0 + breg[4 * a], dy = s1 + breg[4 * a + 1];
        float dw = s2 + breg[4 * a + 2], dh = s3 + breg[4 * a + 3];
        int wi = p % W_, hi = p / W_;
        const double SC[3] = {32.0, 64.0, 128.0};
        const double RT[3] = {0.5, 1.0, 2.0};
        double sd = SC[a / 3], rd = RT[a % 3];
        double wb = sd * sqrt(1.0 / rd), hb = sd * sqrt(rd);
        float bx1 = (float)(-wb * 0.5), by1 = (float)(-hb * 0.5);
        float bx2 = (float)(wb * 0.5),  by2 = (float)(hb * 0.5);
        float cxs = ((float)wi + 0.5f) * 4.0f, cys = ((float)hi + 0.5f) * 4.0f;
        float x1a = cxs + bx1, y1a = cys + by1, x2a = cxs + bx2, y2a = cys + by2;
        float wa = x2a - x1a, ha = y2a - y1a;
        float cxa = x1a + 0.5f * wa, cya = y1a + 0.5f * ha;
        float cx = dx * wa + cxa, cy = dy * ha + cya;
        float ww = expf(dw) * wa, hh = expf(dh) * ha;
        float X1 = cx - 0.5f * ww, Y1 = cy - 0.5f * hh;
        float X2 = cx + 0.5f * ww, Y2 = cy + 0.5f * hh;
        float Wf = (float)(*imw), Hf = (float)(*imh);
        X1 = fminf(fmaxf(X1, 0.f), Wf); Y1 = fminf(fmaxf(Y1, 0.f), Hf);
        X2 = fminf(fmaxf(X2, 0.f), Wf); Y2 = fminf(fmaxf(Y2, 0.f), Hf);
        boxes[4 * r] = X1; boxes[4 * r + 1] = Y1; boxes[4 * r + 2] = X2; boxes[4 * r + 3] = Y2;
        valid[r] = ((X2 - X1) >= 1.0f && (Y2 - Y1) >= 1.0f) ? 1 : 0;
    }
}

// ---- NMS IoU bitmask. Lower-triangle blocks skipped (never read). ----
__global__ __launch_bounds__(256) void k_mask(const float* __restrict__ boxes,
                                              unsigned long long* __restrict__ mask) {
    __shared__ float jb[256];
    int jw = blockIdx.x;
    if (jw * 64 + 63 < (int)blockIdx.y * 256) return;   // never-read region
    int i = blockIdx.y * 256 + threadIdx.x;
    {
        int idx = jw * 256 + threadIdx.x;
        jb[threadIdx.x] = (idx < PRE_N * 4) ? boxes[idx] : 0.f;
    }
    __syncthreads();
    if (i >= PRE_N) return;
    float4 ab = *(const float4*)&boxes[4 * i];
    float ax1 = ab.x, ay1 = ab.y, ax2 = ab.z, ay2 = ab.w;
    float aarea = (ax2 - ax1) * (ay2 - ay1);
    unsigned long long m = 0;
    int jbase = jw * 64;
    for (int b = 0; b < 64; b++) {
        int j = jbase + b;
        if (j <= i || j >= PRE_N) continue;
        float bx1 = jb[4 * b], by1 = jb[4 * b + 1], bx2 = jb[4 * b + 2], by2 = jb[4 * b + 3];
        float barea = (bx2 - bx1) * (by2 - by1);
        float xx1 = fmaxf(ax1, bx1), yy1 = fmaxf(ay1, by1);
        float xx2 = fminf(ax2, bx2), yy2 = fminf(ay2, by2);
        float w = fmaxf(xx2 - xx1, 0.f), h = fmaxf(yy2 - yy1, 0.f);
        float inter = w * h;
        float iou = inter / (aarea + barea - inter + 1e-9f);
        if (iou > 0.7f) m |= (1ull << b);
    }
    mask[(size_t)i * NWORDS + jw] = m;
}

// ---- greedy scan: serial walk on wave 0 via register diag rows + shfl ----
__global__ __launch_bounds__(256) void k_scan_nms(const unsigned long long* __restrict__ mask,
                                                  const int* __restrict__ valid,
                                                  const float* __restrict__ boxes,
                                                  float* __restrict__ out) {
    __shared__ unsigned long long diag[NWORDS][64];   // 48,128 B
    __shared__ unsigned long long removed[NWORDS];
    __shared__ unsigned long long validw[NWORDS];
    __shared__ int keepList[POST_N];
    __shared__ int cnt;
    __shared__ unsigned long long keptbits;
    int t = threadIdx.x;
    if (t < NWORDS) { removed[t] = 0ull; validw[t] = 0ull; }
    if (t == 0) cnt = 0;
    __syncthreads();
    for (int l = t; l < NWORDS * 64; l += 256) {
        int w = l >> 6, b = l & 63;
        int i = w * 64 + b;
        diag[w][b] = (i < PRE_N) ? mask[(size_t)i * NWORDS + w] : 0ull;
    }
    for (int i = t; i < PRE_N; i += 256)
        if (valid[i]) atomicOr(&validw[i >> 6], 1ull << (i & 63));
    __syncthreads();
    for (int w = 0; w < NWORDS; w++) {
        unsigned long long candw = validw[w] & ~removed[w];
        if (!candw) continue;
        if (t < 64) {
            unsigned long long mydiag = diag[w][t];   // lane t owns row (w*64+t)'s word w
            unsigned long long cand = candw;
            unsigned long long kb = 0ull;
            int c = cnt;
            while (cand && c < POST_N) {
                int b = __ffsll((unsigned long long)cand) - 1;
                unsigned long long sup = __shfl(mydiag, b);   // register, ~5 cyc
                if (t == 0) keepList[c] = w * 64 + b;
                c++;
                kb |= 1ull << b;
                cand &= ~(1ull << b);
                cand &= ~sup;
            }
            if (t == 0) { cnt = c; keptbits = kb; }
        }
        __syncthreads();
        if (cnt >= POST_N) break;
        unsigned long long kb = keptbits;
        if (kb) {
            for (int w2 = w + 1 + t; w2 < NWORDS; w2 += 256) {
                unsigned long long acc2 = removed[w2];
                unsigned long long tt = kb;
                while (tt) {
                    int b = __ffsll((unsigned long long)tt) - 1;
                    tt &= tt - 1;
                    acc2 |= mask[(size_t)(w * 64 + b) * NWORDS + w2];
                }
                removed[w2] = acc2;
            }
        }
        __syncthreads();
    }
    __syncthreads();
    int c = cnt;
    for (int e = t; e < POST_N * 4; e += 256) {
        int r = e >> 2;
        out[e] = (r < c) ? boxes[4 * keepList[r] + (e & 3)] : 0.f;
    }
}

extern "C" void kernel_launch(void* const* d_in, const int* in_sizes, int n_in,
                              void* d_out, int out_size, void* d_ws, size_t ws_size,
                              hipStream_t stream) {
    const float* feature = (const float*)d_in[0];
    const float* w1   = (const float*)d_in[1];
    const float* b1   = (const float*)d_in[2];
    const float* wcls = (const float*)d_in[3];
    const float* bcls = (const float*)d_in[4];
    const float* wreg = (const float*)d_in[5];
    const float* breg = (const float*)d_in[6];
    const int* imh = (const int*)d_in[7];
    const int* imw = (const int*)d_in[8];

    char* ws = (char*)d_ws;
    float* xbuf  = (float*)(ws + X_OFF);
    float* conf  = (float*)(ws + CONF_OFF);
    unsigned* scal  = (unsigned*)(ws + SCAL_OFF);
    unsigned long long* sel = (unsigned long long*)(ws + SEL_OFF);
    unsigned* topidx = (unsigned*)(ws + TOPIDX_OFF);
    float* boxes = (float*)(ws + BOXES_OFF);
    int* valid   = (int*)(ws + VALID_OFF);
    unsigned long long* mask = (unsigned long long*)(ws + MASK_OFF);
    float* w1r = (float*)(ws + MASK_OFF);          // dead after k_conv1; overwritten by k_mask
    unsigned* histc = (unsigned*)(ws + HISTC_OFF); // 8 segments; dead after k_scan
    float* wcr = (float*)(ws + WCR_OFF);
    float* xt  = (ws_size >= WS_NEED_XT) ? (float*)(ws + XT_OFF) : (float*)0;
    float* outF = (float*)d_out;

    hipLaunchKernelGGL(k_repack, dim3(2304), dim3(256), 0, stream, w1, w1r, histc);
    hipLaunchKernelGGL(k_conv1,  dim3(9, 25, 8), dim3(256), 0, stream,
                       feature, w1r, b1, xbuf, xt, scal, sel, wcls, wcr);
    hipLaunchKernelGGL(k_cls,    dim3(213),  dim3(256), 0, stream, xbuf, wcr, bcls, conf, histc);
    hipLaunchKernelGGL(k_scan,   dim3(1),    dim3(1024), 0, stream, histc, scal);
    hipLaunchKernelGGL(k_gather, dim3(1913), dim3(256), 0, stream, conf, scal, sel);
    hipLaunchKernelGGL(k_rank,   dim3(64),   dim3(256), 0, stream, scal, sel, topidx);
    hipLaunchKernelGGL(k_prop,   dim3(1500), dim3(256), 0, stream, xbuf, xt, wreg, breg, topidx, imh, imw, boxes, valid);
    hipLaunchKernelGGL(k_mask,   dim3(NWORDS, 24), dim3(256), 0, stream, boxes, mask);
    hipLaunchKernelGGL(k_scan_nms, dim3(1), dim3(256), 0, stream, mask, valid, boxes, outF);
}

// Round 14
// 1434.960 us; speedup vs baseline: 1.1871x; 1.0177x over previous
//
#include <hip/hip_runtime.h>
#include <hip/hip_bf16.h>
#include <math.h>

#define H_ 200
#define W_ 272
#define C_ 256
#define HW 54400
#define NANCH 489600
#define PRE_N 6000
#define POST_N 1000
#define NWORDS 94    // ceil(6000/64)
#define CHUNK_W 2720 // 8 ic * 10 rows * 34 cols halo
#define SELCAP 16384
#define NSEG 8       // histogram privatization copies (R10-proven; 16 regressed in R12)

// ---- workspace layout (bytes) ----
#define X_OFF       0ull                 // 256*54400*4 = 55,705,600
#define CONF_OFF    55705600ull          // 489600*4   =  1,958,400
#define HIST1_OFF   57664000ull          // 65536*4 (unused since R10)
#define SEL_OFF     57926144ull          // 16384*8    =    131,072
#define SCAL_OFF    58188288ull          // 64*4
#define TOPIDX_OFF  58254080ull          // 6000*4
#define BOXES_OFF   58278080ull          // 6000*4*4
#define VALID_OFF   58374080ull          // 6000*4
#define MASK_OFF    58398080ull          // 6000*94*8 = 4,512,000 (w1r + histc live here pre-k_mask)
#define HISTC_OFF   60757376ull          // MASK_OFF + 2,359,296 (w1r); 8*65536*4 = 2,097,152
#define WCR_OFF     65269376ull          // 9*256*4
#define XT_OFF      65278592ull          // optional: 54400*256*4 = 55,705,600 (transposed x)
#define WS_NEED_XT  (XT_OFF + 55705600ull)

__device__ __forceinline__ unsigned fkey(float fv) {
    unsigned u = __float_as_uint(fv);
    return (u & 0x80000000u) ? ~u : (u | 0x80000000u);  // monotone: bigger float -> bigger key
}

// ---- weight repack + histogram-segment zeroing (R10-exact). ----
__global__ __launch_bounds__(256) void k_repack(const float* __restrict__ w1,
                                                float* __restrict__ w1r,
                                                unsigned* __restrict__ histc) {
    int d = blockIdx.x * 256 + threadIdx.x;   // 589,824 total
    if (d < NSEG * 65536) histc[d] = 0u;
    int o = d & 7;
    int q = d >> 3;            // icg*9 + t
    int t = q % 9;
    int icg = q / 9;           // wg8*256 + ic
    int wg8 = icg >> 8, ic = icg & 255;
    w1r[d] = w1[((size_t)(wg8 * 8 + o) * 256 + ic) * 9 + t];
}

// ---- 3x3 conv + bias + relu. R2-proven loop (DO NOT change the body:
// R1/R3/R4/R6 regressed; no fusion/fences: R11 regressed).
// R14: XCD-aware sibling clustering. The 8 oc-sibling blocks of a spatial
// tile stream the SAME 348KB of f; old grid put them 225 dispatch slots
// apart on different XCDs -> 8x refetch (FETCH=541MB). New 1-D mapping
// lid = tile%8 | z<<3 | (tile/8)<<6 keeps lid%8 (XCD, round-robin) constant
// across siblings and packs them within 64 dispatch slots -> L2 sharing.
// Per-block (bx,by,z) identical to before -> bitwise-identical output. ----
__global__ __launch_bounds__(256) void k_conv1(const float* __restrict__ f,
                                               const float* __restrict__ w1r,
                                               const float* __restrict__ b1,
                                               float* __restrict__ xo,
                                               float* __restrict__ xt,
                                               unsigned* __restrict__ scal,
                                               unsigned long long* __restrict__ sel,
                                               const float* __restrict__ wcls,
                                               float* __restrict__ wcr) {
    __shared__ __align__(16) float sI[2][2880];   // 2 x 11,520 B
    int tid = threadIdx.x;
    int lid = blockIdx.x;                 // 1856 blocks (56 holes exit after init)
    // workspace init: 64 scal words + 32768 sel-words (raw lid; holes included)
    {
        int g = lid * 256 + tid;
        if (g < 64) scal[g] = 0u;
        else if (g < 32832) ((unsigned*)sel)[g - 64] = 0xFFFFFFFFu;
    }
    if (lid == 0) {
        for (int e = tid; e < 2304; e += 256) {
            int a = e / 256, c = e % 256;
            wcr[c * 9 + a] = wcls[e];
        }
    }
    int zc   = (lid >> 3) & 7;                    // oc z-group, [0,8)
    int tile = ((lid >> 6) << 3) | (lid & 7);     // spatial tile, lid%8 = tile%8
    if (tile >= 225) return;                      // hole blocks
    int bx = tile % 9, by = tile / 9;

    int lane = tid & 63;
    int wgl = __builtin_amdgcn_readfirstlane(tid >> 6);
    int xg = lane & 7;
    int yg = lane >> 3;
    int X0 = bx * 32;
    int Y0 = by * 8;
    int wg = zc * 4 + wgl;   // oc-group of 8, wave-uniform
    int y = Y0 + yg;
    int xbase = X0 + xg * 4;

    int off[11]; int lds[11]; bool ok[11];
#pragma unroll
    for (int it = 0; it < 11; it++) {
        int l = tid + it * 256;
        int ci = l / 340; int r = l - ci * 340; int ry = r / 34; int rx = r - ry * 34;
        int gx = X0 - 1 + rx, gy = Y0 - 1 + ry;
        ok[it] = (l < CHUNK_W) && gx >= 0 && gx < W_ && gy >= 0 && gy < H_;
        off[it] = ci * HW + gy * W_ + gx;
        lds[it] = (ci * 10 + ry) * 36 + rx;
    }
    float rbuf[11];
#pragma unroll
    for (int it = 0; it < 11; it++)
        rbuf[it] = ok[it] ? f[off[it]] : 0.f;
#pragma unroll
    for (int it = 0; it < 11; it++)
        if (tid + it * 256 < CHUNK_W) sI[0][lds[it]] = rbuf[it];
    __syncthreads();

    float acc[8][4];
#pragma unroll
    for (int o = 0; o < 8; o++)
#pragma unroll
        for (int i = 0; i < 4; i++) acc[o][i] = 0.f;

    const float* wbase = w1r + (size_t)wg * (256 * 72);  // repacked, wave-uniform

    int cur = 0;
    for (int ic0 = 0; ic0 < 256; ic0 += 8) {
        if (ic0 < 248) {
            const float* fn = f + (size_t)(ic0 + 8) * HW;
#pragma unroll
            for (int it = 0; it < 11; it++)
                rbuf[it] = ok[it] ? fn[off[it]] : 0.f;
        }
        const float* sbuf = sI[cur];
        for (int ci = 0; ci < 8; ci++) {
            const float* wci = wbase + (ic0 + ci) * 72;   // 9 taps x 8 oc, contiguous
#pragma unroll
            for (int ky = 0; ky < 3; ky++) {
                const float* irow = &sbuf[(ci * 10 + yg + ky) * 36 + xg * 4];
                float4 va = *(const float4*)irow;
                float2 vb = *(const float2*)(irow + 4);
                float in[6] = {va.x, va.y, va.z, va.w, vb.x, vb.y};
#pragma unroll
                for (int kx = 0; kx < 3; kx++) {
                    const float* w8 = wci + (ky * 3 + kx) * 8;
#pragma unroll
                    for (int o = 0; o < 8; o++) {
                        float w = w8[o];   // s_load from contiguous 32B group
#pragma unroll
                        for (int i = 0; i < 4; i++)
                            acc[o][i] = fmaf(w, in[i + kx], acc[o][i]);
                    }
                }
            }
        }
        if (ic0 < 248) {
#pragma unroll
            for (int it = 0; it < 11; it++)
                if (tid + it * 256 < CHUNK_W) sI[cur ^ 1][lds[it]] = rbuf[it];
        }
        __syncthreads();
        cur ^= 1;
    }
    // epilogue: same per-element ops/order as before (bias add, relu)
    float vout[8][4];
#pragma unroll
    for (int o = 0; o < 8; o++) {
        float bv = b1[wg * 8 + o];
#pragma unroll
        for (int i = 0; i < 4; i++)
            vout[o][i] = fmaxf(acc[o][i] + bv, 0.f);
    }
#pragma unroll
    for (int o = 0; o < 8; o++) {
        int oc = wg * 8 + o;
        float* orow = xo + (size_t)oc * HW + y * W_ + xbase;
        if (xbase + 3 < W_) {
            *(float4*)orow = make_float4(vout[o][0], vout[o][1], vout[o][2], vout[o][3]);
        } else {
            for (int i = 0; i < 4; i++)
                if (xbase + i < W_) orow[i] = vout[o][i];
        }
    }
    if (xt) {   // transposed copy (identical values, different address)
#pragma unroll
        for (int i = 0; i < 4; i++) {
            if (xbase + i < W_) {
                size_t px = (size_t)(y * W_ + xbase + i);
                *(float4*)&xt[px * 256 + wg * 8] =
                    make_float4(vout[0][i], vout[1][i], vout[2][i], vout[3][i]);
                *(float4*)&xt[px * 256 + wg * 8 + 4] =
                    make_float4(vout[4][i], vout[5][i], vout[6][i], vout[7][i]);
            }
        }
    }
}

// ---- 1x1 cls conv -> conf[p*9+a], fused radix histogram.
// ILP-8 prefetch (R9); 8-way segmented histogram (R10, proven -66us). ----
__global__ __launch_bounds__(256) void k_cls(const float* __restrict__ x,
                                             const float* __restrict__ wcr,
                                             const float* __restrict__ bc,
                                             float* __restrict__ conf,
                                             unsigned* __restrict__ histc) {
    int p = blockIdx.x * 256 + threadIdx.x;
    if (p >= HW) return;
    unsigned* myh = histc + (blockIdx.x & (NSEG - 1)) * 65536;
    float acc[9];
#pragma unroll
    for (int a = 0; a < 9; a++) acc[a] = 0.f;
    for (int c0 = 0; c0 < 256; c0 += 8) {
        float xv8[8];
#pragma unroll
        for (int j = 0; j < 8; j++)
            xv8[j] = x[(c0 + j) * HW + p];     // 8 independent loads in flight
#pragma unroll
        for (int j = 0; j < 8; j++) {
            const float* wp = wcr + (c0 + j) * 9;  // uniform -> s_load
#pragma unroll
            for (int a = 0; a < 9; a++) acc[a] = fmaf(wp[a], xv8[j], acc[a]);
        }
    }
#pragma unroll
    for (int a = 0; a < 9; a++) {
        float v = acc[a] + bc[a];
        conf[p * 9 + a] = v;
        atomicAdd(&myh[fkey(v) >> 16], 1u);
    }
}

// ---- descending scan over the segment-summed 65536-bin histogram. ----
__global__ __launch_bounds__(1024) void k_scan(const unsigned* __restrict__ histc,
                                               unsigned* scal) {
    __shared__ unsigned ssum[1024];
    int t = threadIdx.x;
    int base = 65535 - t * 64;
    unsigned s = 0;
    for (int seg = 0; seg < NSEG; seg++) {
        const uint4* hp = (const uint4*)(histc + seg * 65536 + (base - 63));
#pragma unroll
        for (int k = 0; k < 16; k++) { uint4 v = hp[k]; s += v.x + v.y + v.z + v.w; }
    }
    ssum[t] = s;
    __syncthreads();
    for (int off = 1; off < 1024; off <<= 1) {
        unsigned v = (t >= off) ? ssum[t - off] : 0u;
        __syncthreads();
        ssum[t] += v;
        __syncthreads();
    }
    unsigned incl = ssum[t], excl = incl - s;
    if (excl < 6000u && 6000u <= incl) {
        unsigned run = excl;
        bool found = false;
        for (int pass = 0; pass < 2 && !found; pass++) {
            unsigned c32[32];
#pragma unroll
            for (int j = 0; j < 32; j++) {
                int idx = base - (pass * 32 + j);
                unsigned cj = 0;
#pragma unroll
                for (int seg = 0; seg < NSEG; seg++) cj += histc[seg * 65536 + idx];
                c32[j] = cj;
            }
            for (int j = 0; j < 32; j++) {
                if (run + c32[j] >= 6000u) {
                    scal[0] = (unsigned)(base - (pass * 32 + j));
                    scal[1] = run;
                    found = true;
                    break;
                }
                run += c32[j];
            }
        }
    }
}

// ---- single-pass gather: block-aggregated atomics (R10, proven -66us). ----
__global__ __launch_bounds__(256) void k_gather(const float* __restrict__ conf,
                                                unsigned* scal, unsigned long long* sel) {
    __shared__ unsigned lcA, lcB, bA, bB;
    int n = blockIdx.x * 256 + threadIdx.x;
    bool inr = n < NANCH;
    if (threadIdx.x == 0) { lcA = 0u; lcB = 0u; }
    __syncthreads();
    unsigned B1 = scal[0], cnt1 = scal[1];
    unsigned key = 0, off = 0;
    int cls = 0;
    if (inr) {
        key = fkey(conf[n]);
        unsigned pre = key >> 16;
        if (pre > B1)       { cls = 1; off = atomicAdd(&lcA, 1u); }
        else if (pre == B1) { cls = 2; off = atomicAdd(&lcB, 1u); }
    }
    __syncthreads();
    if (threadIdx.x == 0) {
        bA = lcA ? atomicAdd(&scal[4], lcA) : 0u;
        bB = lcB ? atomicAdd(&scal[36], lcB) : 0u;
    }
    __syncthreads();
    if (cls) {
        unsigned long long kk = ((unsigned long long)(~key) << 32) | (unsigned)n;  // smaller = better
        if (cls == 1) {
            sel[bA + off] = kk;                  // [0, cnt1) by construction
        } else {
            unsigned pos = cnt1 + bB + off;
            if (pos < SELCAP) sel[pos] = kk;
        }
    }
}

// ---- exact rank by pairwise comparison over [0, SELCAP) with early-out ----
__global__ __launch_bounds__(256) void k_rank(const unsigned* __restrict__ scal,
                                              const unsigned long long* __restrict__ sel,
                                              unsigned* __restrict__ topidx) {
    __shared__ unsigned long long tile[2048];
    unsigned filled = scal[1] + scal[36];
    if (filled > SELCAP) filled = SELCAP;
    int i = blockIdx.x * 256 + threadIdx.x;
    unsigned long long mykey = sel[i];
    int rank = 0;
    for (int t0 = 0; t0 < SELCAP; t0 += 2048) {
        if (t0 >= (int)filled) break;   // uniform across block
        __syncthreads();
        for (int l = threadIdx.x; l < 2048; l += 256)
            tile[l] = sel[t0 + l];
        __syncthreads();
        for (int l = 0; l < 2048; l += 4) {
            ulonglong2 p = *(const ulonglong2*)&tile[l];
            ulonglong2 q = *(const ulonglong2*)&tile[l + 2];
            rank += (p.x < mykey) + (p.y < mykey) + (q.x < mykey) + (q.y < mykey);
        }
    }
    if (i < (int)filled && rank < PRE_N)
        topidx[rank] = (unsigned)(mykey & 0xFFFFFFFFull);
}

// ---- per-proposal: reg conv (4 channels), anchor, decode, clip, valid. ----
__global__ __launch_bounds__(256) void k_prop(const float* __restrict__ x,
                                              const float* __restrict__ xt,
                                              const float* __restrict__ wreg,
                                              const float* __restrict__ breg,
                                              const unsigned* __restrict__ topidx,
                                              const int* __restrict__ imh, const int* __restrict__ imw,
                                              float* __restrict__ boxes, int* __restrict__ valid) {
    int r = blockIdx.x * 4 + (threadIdx.x >> 6);   // 1500 blocks x 4 waves = 6000
    int lane = threadIdx.x & 63;
    unsigned n = topidx[r];
    int a = (int)(n % 9u); int p = (int)(n / 9u);
    const float* wr = wreg + (4 * a) * 256;
    float xv4[4], w0[4], w1[4], w2[4], w3[4];
    if (xt) {
        const float* xp = xt + (size_t)p * 256;
#pragma unroll
        for (int j = 0; j < 4; j++) {
            int c = lane + 64 * j;
            xv4[j] = xp[c];
            w0[j] = wr[c]; w1[j] = wr[256 + c]; w2[j] = wr[512 + c]; w3[j] = wr[768 + c];
        }
    } else {
#pragma unroll
        for (int j = 0; j < 4; j++) {
            int c = lane + 64 * j;
            xv4[j] = x[c * HW + p];
            w0[j] = wr[c]; w1[j] = wr[256 + c]; w2[j] = wr[512 + c]; w3[j] = wr[768 + c];
        }
    }
    float s0 = 0, s1 = 0, s2 = 0, s3 = 0;
#pragma unroll
    for (int j = 0; j < 4; j++) {
        s0 = fmaf(w0[j], xv4[j], s0);
        s1 = fmaf(w1[j], xv4[j], s1);
        s2 = fmaf(w2[j], xv4[j], s2);
        s3 = fmaf(w3[j], xv4[j], s3);
    }
#pragma unroll
    for (int off = 32; off >= 1; off >>= 1) {
        s0 += __shfl_down(s0, off);
        s1 += __shfl_down(s1, off);
        s2 += __shfl_down(s2, off);
        s3 += __shfl_down(s3, off);
    }
    if (lane == 0) {
        float dx = s0 + breg[4 * a], dy = s1 + breg[4 * a + 1];
        float dw = s2 + breg[4 * a + 2], dh = s3 + breg[4 * a + 3];
        int wi = p % W_, hi = p / W_;
        const double SC[3] = {32.0, 64.0, 128.0};
        const double RT[3] = {0.5, 1.0, 2.0};
        double sd = SC[a / 3], rd = RT[a % 3];
        double wb = sd * sqrt(1.0 / rd), hb = sd * sqrt(rd);
        float bx1 = (float)(-wb * 0.5), by1 = (float)(-hb * 0.5);
        float bx2 = (float)(wb * 0.5),  by2 = (float)(hb * 0.5);
        float cxs = ((float)wi + 0.5f) * 4.0f, cys = ((float)hi + 0.5f) * 4.0f;
        float x1a = cxs + bx1, y1a = cys + by1, x2a = cxs + bx2, y2a = cys + by2;
        float wa = x2a - x1a, ha = y2a - y1a;
        float cxa = x1a + 0.5f * wa, cya = y1a + 0.5f * ha;
        float cx = dx * wa + cxa, cy = dy * ha + cya;
        float ww = expf(dw) * wa, hh = expf(dh) * ha;
        float X1 = cx - 0.5f * ww, Y1 = cy - 0.5f * hh;
        float X2 = cx + 0.5f * ww, Y2 = cy + 0.5f * hh;
        float Wf = (float)(*imw), Hf = (float)(*imh);
        X1 = fminf(fmaxf(X1, 0.f), Wf); Y1 = fminf(fmaxf(Y1, 0.f), Hf);
        X2 = fminf(fmaxf(X2, 0.f), Wf); Y2 = fminf(fmaxf(Y2, 0.f), Hf);
        boxes[4 * r] = X1; boxes[4 * r + 1] = Y1; boxes[4 * r + 2] = X2; boxes[4 * r + 3] = Y2;
        valid[r] = ((X2 - X1) >= 1.0f && (Y2 - Y1) >= 1.0f) ? 1 : 0;
    }
}

// ---- NMS IoU bitmask. Lower-triangle blocks skipped (never read). ----
__global__ __launch_bounds__(256) void k_mask(const float* __restrict__ boxes,
                                              unsigned long long* __restrict__ mask) {
    __shared__ float jb[256];
    int jw = blockIdx.x;
    if (jw * 64 + 63 < (int)blockIdx.y * 256) return;   // never-read region
    int i = blockIdx.y * 256 + threadIdx.x;
    {
        int idx = jw * 256 + threadIdx.x;
        jb[threadIdx.x] = (idx < PRE_N * 4) ? boxes[idx] : 0.f;
    }
    __syncthreads();
    if (i >= PRE_N) return;
    float4 ab = *(const float4*)&boxes[4 * i];
    float ax1 = ab.x, ay1 = ab.y, ax2 = ab.z, ay2 = ab.w;
    float aarea = (ax2 - ax1) * (ay2 - ay1);
    unsigned long long m = 0;
    int jbase = jw * 64;
    for (int b = 0; b < 64; b++) {
        int j = jbase + b;
        if (j <= i || j >= PRE_N) continue;
        float bx1 = jb[4 * b], by1 = jb[4 * b + 1], bx2 = jb[4 * b + 2], by2 = jb[4 * b + 3];
        float barea = (bx2 - bx1) * (by2 - by1);
        float xx1 = fmaxf(ax1, bx1), yy1 = fmaxf(ay1, by1);
        float xx2 = fminf(ax2, bx2), yy2 = fminf(ay2, by2);
        float w = fmaxf(xx2 - xx1, 0.f), h = fmaxf(yy2 - yy1, 0.f);
        float inter = w * h;
        float iou = inter / (aarea + barea - inter + 1e-9f);
        if (iou > 0.7f) m |= (1ull << b);
    }
    mask[(size_t)i * NWORDS + jw] = m;
}

// ---- greedy scan: serial walk on wave 0 via register diag rows + shfl ----
__global__ __launch_bounds__(256) void k_scan_nms(const unsigned long long* __restrict__ mask,
                                                  const int* __restrict__ valid,
                                                  const float* __restrict__ boxes,
                                                  float* __restrict__ out) {
    __shared__ unsigned long long diag[NWORDS][64];   // 48,128 B
    __shared__ unsigned long long removed[NWORDS];
    __shared__ unsigned long long validw[NWORDS];
    __shared__ int keepList[POST_N];
    __shared__ int cnt;
    __shared__ unsigned long long keptbits;
    int t = threadIdx.x;
    if (t < NWORDS) { removed[t] = 0ull; validw[t] = 0ull; }
    if (t == 0) cnt = 0;
    __syncthreads();
    for (int l = t; l < NWORDS * 64; l += 256) {
        int w = l >> 6, b = l & 63;
        int i = w * 64 + b;
        diag[w][b] = (i < PRE_N) ? mask[(size_t)i * NWORDS + w] : 0ull;
    }
    for (int i = t; i < PRE_N; i += 256)
        if (valid[i]) atomicOr(&validw[i >> 6], 1ull << (i & 63));
    __syncthreads();
    for (int w = 0; w < NWORDS; w++) {
        unsigned long long candw = validw[w] & ~removed[w];
        if (!candw) continue;
        if (t < 64) {
            unsigned long long mydiag = diag[w][t];   // lane t owns row (w*64+t)'s word w
            unsigned long long cand = candw;
            unsigned long long kb = 0ull;
            int c = cnt;
            while (cand && c < POST_N) {
                int b = __ffsll((unsigned long long)cand) - 1;
                unsigned long long sup = __shfl(mydiag, b);   // register, ~5 cyc
                if (t == 0) keepList[c] = w * 64 + b;
                c++;
                kb |= 1ull << b;
                cand &= ~(1ull << b);
                cand &= ~sup;
            }
            if (t == 0) { cnt = c; keptbits = kb; }
        }
        __syncthreads();
        if (cnt >= POST_N) break;
        unsigned long long kb = keptbits;
        if (kb) {
            for (int w2 = w + 1 + t; w2 < NWORDS; w2 += 256) {
                unsigned long long acc2 = removed[w2];
                unsigned long long tt = kb;
                while (tt) {
                    int b = __ffsll((unsigned long long)tt) - 1;
                    tt &= tt - 1;
                    acc2 |= mask[(size_t)(w * 64 + b) * NWORDS + w2];
                }
                removed[w2] = acc2;
            }
        }
        __syncthreads();
    }
    __syncthreads();
    int c = cnt;
    for (int e = t; e < POST_N * 4; e += 256) {
        int r = e >> 2;
        out[e] = (r < c) ? boxes[4 * keepList[r] + (e & 3)] : 0.f;
    }
}

extern "C" void kernel_launch(void* const* d_in, const int* in_sizes, int n_in,
                              void* d_out, int out_size, void* d_ws, size_t ws_size,
                              hipStream_t stream) {
    const float* feature = (const float*)d_in[0];
    const float* w1   = (const float*)d_in[1];
    const float* b1   = (const float*)d_in[2];
    const float* wcls = (const float*)d_in[3];
    const float* bcls = (const float*)d_in[4];
    const float* wreg = (const float*)d_in[5];
    const float* breg = (const float*)d_in[6];
    const int* imh = (const int*)d_in[7];
    const int* imw = (const int*)d_in[8];

    char* ws = (char*)d_ws;
    float* xbuf  = (float*)(ws + X_OFF);
    float* conf  = (float*)(ws + CONF_OFF);
    unsigned* scal  = (unsigned*)(ws + SCAL_OFF);
    unsigned long long* sel = (unsigned long long*)(ws + SEL_OFF);
    unsigned* topidx = (unsigned*)(ws + TOPIDX_OFF);
    float* boxes = (float*)(ws + BOXES_OFF);
    int* valid   = (int*)(ws + VALID_OFF);
    unsigned long long* mask = (unsigned long long*)(ws + MASK_OFF);
    float* w1r = (float*)(ws + MASK_OFF);          // dead after k_conv1; overwritten by k_mask
    unsigned* histc = (unsigned*)(ws + HISTC_OFF); // 8 segments; dead after k_scan
    float* wcr = (float*)(ws + WCR_OFF);
    float* xt  = (ws_size >= WS_NEED_XT) ? (float*)(ws + XT_OFF) : (float*)0;
    float* outF = (float*)d_out;

    hipLaunchKernelGGL(k_repack, dim3(2304), dim3(256), 0, stream, w1, w1r, histc);
    hipLaunchKernelGGL(k_conv1,  dim3(1856), dim3(256), 0, stream,
                       feature, w1r, b1, xbuf, xt, scal, sel, wcls, wcr);
    hipLaunchKernelGGL(k_cls,    dim3(213),  dim3(256), 0, stream, xbuf, wcr, bcls, conf, histc);
    hipLaunchKernelGGL(k_scan,   dim3(1),    dim3(1024), 0, stream, histc, scal);
    hipLaunchKernelGGL(k_gather, dim3(1913), dim3(256), 0, stream, conf, scal, sel);
    hipLaunchKernelGGL(k_rank,   dim3(64),   dim3(256), 0, stream, scal, sel, topidx);
    hipLaunchKernelGGL(k_prop,   dim3(1500), dim3(256), 0, stream, xbuf, xt, wreg, breg, topidx, imh, imw, boxes, valid);
    hipLaunchKernelGGL(k_mask,   dim3(NWORDS, 24), dim3(256), 0, stream, boxes, mask);
    hipLaunchKernelGGL(k_scan_nms, dim3(1), dim3(256), 0, stream, mask, valid, boxes, outF);
}